// Round 1
// baseline (795.578 us; speedup 1.0000x reference)
//
#include <hip/hip_runtime.h>
#include <hip/hip_bf16.h>
#include <cmath>

// Problem constants
constexpr int Bc = 2, Tc = 4096, Dc = 2048, Hc = 16, HDc = 128;
constexpr int Mrows = Bc * Tc;            // 8192
constexpr int NCHUNK = 32, CHUNK = 128;   // T = NCHUNK * CHUNK

// ---------- small helpers ----------
__device__ __forceinline__ unsigned short f2bf(float x) {
  union { float f; unsigned int u; } v; v.f = x;
  unsigned int r = v.u + 0x7FFFu + ((v.u >> 16) & 1u);  // RNE
  return (unsigned short)(r >> 16);
}
__device__ __forceinline__ float bf2f(unsigned short u) {
  union { unsigned int i; float f; } v; v.i = ((unsigned int)u) << 16;
  return v.f;
}

typedef __attribute__((ext_vector_type(8))) short bf16x8;
typedef __attribute__((ext_vector_type(4))) float f32x4;

__device__ __forceinline__ void gload16(const unsigned short* g, unsigned short* l) {
  __builtin_amdgcn_global_load_lds(
      (const __attribute__((address_space(1))) void*)(const void*)g,
      (__attribute__((address_space(3))) void*)(void*)l,
      16, 0, 0);
}

// ---------- fp32 -> bf16 convert (vectorized) ----------
__global__ void cvt_bf16(const float* __restrict__ in, unsigned short* __restrict__ outp) {
  size_t i = ((size_t)blockIdx.x * 256 + threadIdx.x) * 4;
  float4 f = *(const float4*)(in + i);
  ushort4 u;
  u.x = f2bf(f.x); u.y = f2bf(f.y); u.z = f2bf(f.z); u.w = f2bf(f.w);
  *(ushort4*)(outp + i) = u;
}

// ---------- W [K][N] fp32 -> Wt [N][K] bf16 ----------
__global__ void transpose_cvt(const float* __restrict__ W, unsigned short* __restrict__ Wt) {
  __shared__ float tile[32][33];
  int n0 = blockIdx.x * 32, k0 = blockIdx.y * 32;
  int tx = threadIdx.x & 31, ty = threadIdx.x >> 5;  // ty: 0..7
#pragma unroll
  for (int i = 0; i < 4; ++i)
    tile[ty + 8 * i][tx] = W[(size_t)(k0 + ty + 8 * i) * Dc + n0 + tx];
  __syncthreads();
#pragma unroll
  for (int i = 0; i < 4; ++i)
    Wt[(size_t)(n0 + ty + 8 * i) * Dc + k0 + tx] = f2bf(tile[tx][ty + 8 * i]);
}

// ---------- GEMM: C[M,N] = A[M,K](bf16) * Bt[N,K](bf16)^T ----------
// EPI: 0 = fp32 store, 1 = bf16 store, 2 = bf16(exp(x + eoff))
#define BM 128
#define BN 128
#define BK 32

template <int EPI>
__global__ __launch_bounds__(256) void gemm_bt(
    const unsigned short* __restrict__ A,
    const unsigned short* __restrict__ Bt,
    void* __restrict__ Cout,
    int M, int N, int K, float eoff) {
  __shared__ __align__(16) unsigned short lds_a[BM * BK];
  __shared__ __align__(16) unsigned short lds_b[BN * BK];

  const int tid = threadIdx.x;
  const int wave = tid >> 6;
  const int lane = tid & 63;

  const int nbn = N / BN;
  const int nwg = (M / BM) * nbn;
  // bijective XCD swizzle (nwg % 8 == 0 here)
  const int bid = blockIdx.x;
  const int wgid = (bid & 7) * (nwg >> 3) + (bid >> 3);
  const int bm = wgid / nbn;
  const int bn = wgid % nbn;

  const int wm = wave >> 1, wn = wave & 1;
  const int srow = tid >> 2;            // 0..63
  const int skcol = (tid & 3) * 8;      // 0,8,16,24

  const unsigned short* ga = A + (size_t)(bm * BM + srow) * K + skcol;
  const unsigned short* gb = Bt + (size_t)(bn * BN + srow) * K + skcol;
  const size_t rstep = (size_t)64 * K;

  f32x4 acc[4][4] = {};

  const int fr = lane & 15;
  const int fko = (lane >> 4) * 8;

  for (int kt = 0; kt < K; kt += BK) {
    gload16(ga,         lds_a + wave * 512);
    gload16(ga + rstep, lds_a + 2048 + wave * 512);
    gload16(gb,         lds_b + wave * 512);
    gload16(gb + rstep, lds_b + 2048 + wave * 512);
    ga += BK; gb += BK;
    __syncthreads();

    bf16x8 af[4], bfr[4];
#pragma unroll
    for (int i = 0; i < 4; ++i) {
      af[i]  = *(const bf16x8*)(lds_a + (wm * 64 + i * 16 + fr) * BK + fko);
      bfr[i] = *(const bf16x8*)(lds_b + (wn * 64 + i * 16 + fr) * BK + fko);
    }
#pragma unroll
    for (int mi = 0; mi < 4; ++mi)
#pragma unroll
      for (int ni = 0; ni < 4; ++ni)
        acc[mi][ni] = __builtin_amdgcn_mfma_f32_16x16x32_bf16(af[mi], bfr[ni], acc[mi][ni], 0, 0, 0);
    __syncthreads();
  }

  const int fq = lane >> 4;
#pragma unroll
  for (int mi = 0; mi < 4; ++mi) {
#pragma unroll
    for (int ni = 0; ni < 4; ++ni) {
#pragma unroll
      for (int ii = 0; ii < 4; ++ii) {
        const int row = bm * BM + wm * 64 + mi * 16 + fq * 4 + ii;
        const int col = bn * BN + wn * 64 + ni * 16 + fr;
        const size_t idx = (size_t)row * N + col;
        float v = acc[mi][ni][ii];
        if (EPI == 0) {
          ((float*)Cout)[idx] = v;
        } else if (EPI == 1) {
          ((unsigned short*)Cout)[idx] = f2bf(v);
        } else {
          ((unsigned short*)Cout)[idx] = f2bf(expf(v + eoff));
        }
      }
    }
  }
}

// ---------- dot[b,h,t] = sum_d qp[b,t,h*128+d] * kp[...] ----------
__global__ void dot_kernel(const unsigned short* __restrict__ qp,
                           const unsigned short* __restrict__ kp,
                           float* __restrict__ dotb) {
  int bid = blockIdx.x;            // (b*H + h)*T + t
  int t = bid % Tc;
  int bh = bid / Tc;
  int b = bh / Hc, h = bh % Hc;
  int d = threadIdx.x;             // 0..127
  size_t idx = ((size_t)(b * Tc + t)) * Dc + h * HDc + d;
  float p = bf2f(qp[idx]) * bf2f(kp[idx]);
#pragma unroll
  for (int s = 32; s; s >>= 1) p += __shfl_down(p, s);
  __shared__ float part[2];
  int lane = threadIdx.x & 63, wv = threadIdx.x >> 6;
  if (lane == 0) part[wv] = p;
  __syncthreads();
  if (threadIdx.x == 0) dotb[bid] = part[0] + part[1];
}

// ---------- chunked scan: pass 1 (per-chunk sums) ----------
__global__ void scan_chunks(const float* __restrict__ dotb,
                            const unsigned short* __restrict__ v,
                            float* __restrict__ chks) {
  int bid = blockIdx.x;            // bh*NCHUNK + c
  int c = bid % NCHUNK, bh = bid / NCHUNK;
  int b = bh / Hc, h = bh % Hc;
  int d = threadIdx.x;
  const float* dp = dotb + (size_t)bh * Tc + c * CHUNK;
  const unsigned short* vp = v + ((size_t)(b * Tc + c * CHUNK)) * Dc + h * HDc + d;
  float acc = 0.f;
  for (int t = 0; t < CHUNK; ++t)
    acc += dp[t] * bf2f(vp[(size_t)t * Dc]);
  chks[(size_t)bid * HDc + d] = acc;
}

// ---------- chunked scan: pass 2 (exclusive scan of chunk sums) ----------
__global__ void scan_offsets(float* __restrict__ chks) {
  int bh = blockIdx.x;
  int d = threadIdx.x;
  float run = 0.f;
  for (int c = 0; c < NCHUNK; ++c) {
    size_t idx = ((size_t)bh * NCHUNK + c) * HDc + d;
    float tmp = chks[idx];
    chks[idx] = run;
    run += tmp;
  }
}

// ---------- chunked scan: pass 3 (final prefix + divide by kp, bf16 out) ----------
__global__ void scan_final(const float* __restrict__ dotb,
                           const unsigned short* __restrict__ v,
                           const unsigned short* __restrict__ kp,
                           const float* __restrict__ chks,
                           unsigned short* __restrict__ attn) {
  int bid = blockIdx.x;
  int c = bid % NCHUNK, bh = bid / NCHUNK;
  int b = bh / Hc, h = bh % Hc;
  int d = threadIdx.x;
  const float* dp = dotb + (size_t)bh * Tc + c * CHUNK;
  size_t base = ((size_t)(b * Tc + c * CHUNK)) * Dc + h * HDc + d;
  float acc = chks[(size_t)bid * HDc + d];
  for (int t = 0; t < CHUNK; ++t) {
    size_t idx = base + (size_t)t * Dc;
    acc += dp[t] * bf2f(v[idx]);
    attn[idx] = f2bf(acc / bf2f(kp[idx]));
  }
}

// ---------- launch ----------
extern "C" void kernel_launch(void* const* d_in, const int* in_sizes, int n_in,
                              void* d_out, int out_size, void* d_ws, size_t ws_size,
                              hipStream_t stream) {
  const float* hs = (const float*)d_in[0];
  const float* Wq = (const float*)d_in[1];
  const float* Wk = (const float*)d_in[2];
  const float* Wv = (const float*)d_in[3];
  const float* Wo = (const float*)d_in[4];
  const float* Fq = (const float*)d_in[5];
  const float* Fk = (const float*)d_in[6];
  float* out = (float*)d_out;

  const size_t MD = (size_t)Mrows * Dc;  // 16,777,216
  const size_t DD = (size_t)Dc * Dc;     // 4,194,304

  char* w = (char*)d_ws;
  size_t off = 0;
  auto take = [&](size_t bytes) -> void* {
    void* r = w + off;
    off += (bytes + 255) & ~(size_t)255;
    return r;
  };

  unsigned short* hs_bf = (unsigned short*)take(MD * 2);  // later reused as Qp
  unsigned short* wtq  = (unsigned short*)take(DD * 2);
  unsigned short* wtk  = (unsigned short*)take(DD * 2);
  unsigned short* wtv  = (unsigned short*)take(DD * 2);
  unsigned short* wto  = (unsigned short*)take(DD * 2);
  unsigned short* wtfq = (unsigned short*)take(DD * 2);
  unsigned short* wtfk = (unsigned short*)take(DD * 2);
  unsigned short* Qbf  = (unsigned short*)take(MD * 2);   // later reused as Kp
  unsigned short* Kbf  = (unsigned short*)take(MD * 2);   // later reused as attn
  unsigned short* Vbf  = (unsigned short*)take(MD * 2);
  float* dotb = (float*)take((size_t)Bc * Hc * Tc * 4);
  float* chks = (float*)take((size_t)Bc * Hc * NCHUNK * HDc * 4);

  // aliases (stream-ordered reuse; all safe w.r.t. producer/consumer order)
  unsigned short* Qp = hs_bf;
  unsigned short* Kp = Qbf;
  unsigned short* attnbf = Kbf;

  const float OFF = (float)(-0.5 * log(2048.0) + 1e-6);

  // 1) convert activations
  cvt_bf16<<<(int)(MD / 1024), 256, 0, stream>>>(hs, hs_bf);

  // 2) transpose+convert weights
  dim3 tg(Dc / 32, Dc / 32);
  transpose_cvt<<<tg, 256, 0, stream>>>(Wq, wtq);
  transpose_cvt<<<tg, 256, 0, stream>>>(Wk, wtk);
  transpose_cvt<<<tg, 256, 0, stream>>>(Wv, wtv);
  transpose_cvt<<<tg, 256, 0, stream>>>(Wo, wto);
  transpose_cvt<<<tg, 256, 0, stream>>>(Fq, wtfq);
  transpose_cvt<<<tg, 256, 0, stream>>>(Fk, wtfk);

  const int gblocks = (Mrows / BM) * (Dc / BN);  // 1024

  // 3) Q, K, V projections (bf16 out)
  gemm_bt<1><<<gblocks, 256, 0, stream>>>(hs_bf, wtq, Qbf, Mrows, Dc, Dc, 0.f);
  gemm_bt<1><<<gblocks, 256, 0, stream>>>(hs_bf, wtk, Kbf, Mrows, Dc, Dc, 0.f);
  gemm_bt<1><<<gblocks, 256, 0, stream>>>(hs_bf, wtv, Vbf, Mrows, Dc, Dc, 0.f);

  // 4) feature maps with fused exp epilogue
  gemm_bt<2><<<gblocks, 256, 0, stream>>>(Qbf, wtfq, Qp, Mrows, Dc, Dc, OFF);
  gemm_bt<2><<<gblocks, 256, 0, stream>>>(Kbf, wtfk, Kp, Mrows, Dc, Dc, OFF);

  // 5) per-position dot over each head
  dot_kernel<<<Bc * Hc * Tc, 128, 0, stream>>>(Qp, Kp, dotb);

  // 6) chunked causal cumsum + divide, write bf16 attn (merged layout)
  scan_chunks<<<Bc * Hc * NCHUNK, 128, 0, stream>>>(dotb, Vbf, chks);
  scan_offsets<<<Bc * Hc, 128, 0, stream>>>(chks);
  scan_final<<<Bc * Hc * NCHUNK, 128, 0, stream>>>(dotb, Vbf, Kp, chks, attnbf);

  // 7) output projection (fp32 out)
  gemm_bt<0><<<gblocks, 256, 0, stream>>>(attnbf, wto, out, Mrows, Dc, Dc, 0.f);
}

// Round 2
// 557.696 us; speedup vs baseline: 1.4265x; 1.4265x over previous
//
#include <hip/hip_runtime.h>
#include <hip/hip_bf16.h>
#include <cmath>

// Problem constants
constexpr int Bc = 2, Tc = 4096, Dc = 2048, Hc = 16, HDc = 128;
constexpr int Mrows = Bc * Tc;            // 8192
constexpr int NCHUNK = 32, CHUNK = 128;   // T = NCHUNK * CHUNK

// ---------- small helpers ----------
__device__ __forceinline__ unsigned short f2bf(float x) {
  union { float f; unsigned int u; } v; v.f = x;
  unsigned int r = v.u + 0x7FFFu + ((v.u >> 16) & 1u);  // RNE
  return (unsigned short)(r >> 16);
}
__device__ __forceinline__ float bf2f(unsigned short u) {
  union { unsigned int i; float f; } v; v.i = ((unsigned int)u) << 16;
  return v.f;
}

typedef __attribute__((ext_vector_type(8))) short bf16x8;
typedef __attribute__((ext_vector_type(4))) float f32x4;

__device__ __forceinline__ void gload16(const unsigned short* g, unsigned short* l) {
  __builtin_amdgcn_global_load_lds(
      (const __attribute__((address_space(1))) void*)(const void*)g,
      (__attribute__((address_space(3))) void*)(void*)l,
      16, 0, 0);
}

// ---------- fp32 -> bf16 convert (vectorized) ----------
__global__ void cvt_bf16(const float* __restrict__ in, unsigned short* __restrict__ outp) {
  size_t i = ((size_t)blockIdx.x * 256 + threadIdx.x) * 4;
  float4 f = *(const float4*)(in + i);
  ushort4 u;
  u.x = f2bf(f.x); u.y = f2bf(f.y); u.z = f2bf(f.z); u.w = f2bf(f.w);
  *(ushort4*)(outp + i) = u;
}

// ---------- W [K][N] fp32 -> Wt [N][K] bf16 ----------
__global__ void transpose_cvt(const float* __restrict__ W, unsigned short* __restrict__ Wt) {
  __shared__ float tile[32][33];
  int n0 = blockIdx.x * 32, k0 = blockIdx.y * 32;
  int tx = threadIdx.x & 31, ty = threadIdx.x >> 5;  // ty: 0..7
#pragma unroll
  for (int i = 0; i < 4; ++i)
    tile[ty + 8 * i][tx] = W[(size_t)(k0 + ty + 8 * i) * Dc + n0 + tx];
  __syncthreads();
#pragma unroll
  for (int i = 0; i < 4; ++i)
    Wt[(size_t)(n0 + ty + 8 * i) * Dc + k0 + tx] = f2bf(tile[tx][ty + 8 * i]);
}

// ============================================================================
// 256x256 8-phase GEMM: C[M,N] = A[M,K](bf16, lda) * Bt[N,K](bf16)^T
// K hardcoded 2048. 8 waves (2M x 4N), LDS 128 KiB (2 dbuf x (A,B) x 2 K-half
// slabs of [256][32] bf16). Counted vmcnt(4), setprio around MFMA clusters.
// EPI: 0 = fp32 store, 1 = bf16 store, 2 = bf16(exp(x + eoff))
// ============================================================================
template <int EPI>
__global__ __launch_bounds__(512, 2) void gemm256(
    const unsigned short* __restrict__ A,
    const unsigned short* __restrict__ Bt,
    void* __restrict__ Cout,
    int M, int N, int lda, int ldc, float eoff) {
  constexpr int K = 2048;
  constexpr int NT = K / 64;  // 32 K-tiles
  extern __shared__ unsigned short lds[];  // 65536 ushorts = 128 KiB

  const int tid = threadIdx.x;
  const int lane = tid & 63;
  const int wave = tid >> 6;   // 0..7
  const int wm = wave >> 2;    // 0..1
  const int wn = wave & 3;     // 0..3

  const int nbn = N >> 8;
  const int nwg = (M >> 8) * nbn;
  const int bidx = (int)blockIdx.x;
  const int wgid = (bidx & 7) * (nwg >> 3) + (bidx >> 3);  // XCD swizzle (nwg%8==0)
  const int bm = wgid / nbn;
  const int bn = wgid % nbn;

  // ---- staging addressing: one slab = 256 rows x 32 bf16 (64B rows), 2 gloads
  const int srow = tid >> 2;          // 0..127
  const int scol = (tid & 3) << 3;    // 0,8,16,24 (x8 bf16 = 16B)
  const unsigned short* gA = A + (size_t)(bm * 256 + srow) * lda + scol;
  const unsigned short* gB = Bt + (size_t)(bn * 256 + srow) * K + scol;
  const int sstage = srow * 32 + scol;          // elem offset within slab (j=0)
  const size_t arstep = (size_t)128 * lda;      // +128 rows (j=1)
  const size_t brstep = (size_t)128 * K;

  // ---- fragment read offsets (within a slab)
  const int fr = lane & 15;
  const int fko = (lane >> 4) << 3;   // 0,8,16,24
  const int aoff = (wm * 128 + fr) * 32 + fko;            // + mi*512
  const int boff = 16384 + (wn * 64 + fr) * 32 + fko;     // + ni*512 (B at +16384)

  f32x4 acc[8][4] = {};
  bf16x8 af[8];
  bf16x8 bfr[2];

  // ---- prologue: stage tile 0 into buf0, order [A-kk0, B-kk0, A-kk1, B-kk1]
  {
    const unsigned short* sA = gA;
    const unsigned short* sB = gB;
    gload16(sA,          lds + sstage);
    gload16(sA + arstep, lds + sstage + 4096);
    gload16(sB,          lds + 16384 + sstage);
    gload16(sB + brstep, lds + 16384 + sstage + 4096);
    gload16(sA + 32,          lds + 8192 + sstage);
    gload16(sA + 32 + arstep, lds + 8192 + sstage + 4096);
    gload16(sB + 32,          lds + 8192 + 16384 + sstage);
    gload16(sB + 32 + brstep, lds + 8192 + 16384 + sstage + 4096);
  }
  asm volatile("s_waitcnt vmcnt(4)" ::: "memory");
  __builtin_amdgcn_s_barrier();

  for (int v = 0; v < NT; ++v) {
    const int b = v & 1;
    const int tn = (v + 1) & (NT - 1);            // wrap-stage: harmless reload of tile 0
    const int sb = b * 32768;                      // read buffer base
    const int db = (b ^ 1) * 32768;                // stage (write) buffer base
    const unsigned short* srcA = gA + tn * 64;
    const unsigned short* srcB = gB + tn * 64;

    // ===== phase 1: kk0, ni{0,1} =====
    {
#pragma unroll
      for (int mi = 0; mi < 8; ++mi)
        af[mi] = *(const bf16x8*)(lds + sb + aoff + mi * 512);
      bfr[0] = *(const bf16x8*)(lds + sb + boff);
      bfr[1] = *(const bf16x8*)(lds + sb + boff + 512);
      gload16(srcA,          lds + db + sstage);            // stage A-kk0(tile v+1)
      gload16(srcA + arstep, lds + db + sstage + 4096);
      __builtin_amdgcn_s_barrier();
      asm volatile("s_waitcnt lgkmcnt(0)" ::: "memory");
      __builtin_amdgcn_s_setprio(1);
#pragma unroll
      for (int mi = 0; mi < 8; ++mi) {
        acc[mi][0] = __builtin_amdgcn_mfma_f32_16x16x32_bf16(af[mi], bfr[0], acc[mi][0], 0, 0, 0);
        acc[mi][1] = __builtin_amdgcn_mfma_f32_16x16x32_bf16(af[mi], bfr[1], acc[mi][1], 0, 0, 0);
      }
      __builtin_amdgcn_s_setprio(0);
      __builtin_amdgcn_s_barrier();
    }
    // ===== phase 2: kk0, ni{2,3} (A frags reused) =====
    {
      bfr[0] = *(const bf16x8*)(lds + sb + boff + 1024);
      bfr[1] = *(const bf16x8*)(lds + sb + boff + 1536);
      gload16(srcB,          lds + db + 16384 + sstage);    // stage B-kk0(tile v+1)
      gload16(srcB + brstep, lds + db + 16384 + sstage + 4096);
      asm volatile("s_waitcnt vmcnt(4)" ::: "memory");      // tile v kk1 slabs landed
      __builtin_amdgcn_s_barrier();
      asm volatile("s_waitcnt lgkmcnt(0)" ::: "memory");
      __builtin_amdgcn_s_setprio(1);
#pragma unroll
      for (int mi = 0; mi < 8; ++mi) {
        acc[mi][2] = __builtin_amdgcn_mfma_f32_16x16x32_bf16(af[mi], bfr[0], acc[mi][2], 0, 0, 0);
        acc[mi][3] = __builtin_amdgcn_mfma_f32_16x16x32_bf16(af[mi], bfr[1], acc[mi][3], 0, 0, 0);
      }
      __builtin_amdgcn_s_setprio(0);
      __builtin_amdgcn_s_barrier();
    }
    // ===== phase 3: kk1, ni{0,1} =====
    {
#pragma unroll
      for (int mi = 0; mi < 8; ++mi)
        af[mi] = *(const bf16x8*)(lds + sb + 8192 + aoff + mi * 512);
      bfr[0] = *(const bf16x8*)(lds + sb + 8192 + boff);
      bfr[1] = *(const bf16x8*)(lds + sb + 8192 + boff + 512);
      gload16(srcA + 32,          lds + db + 8192 + sstage);  // stage A-kk1(tile v+1)
      gload16(srcA + 32 + arstep, lds + db + 8192 + sstage + 4096);
      __builtin_amdgcn_s_barrier();
      asm volatile("s_waitcnt lgkmcnt(0)" ::: "memory");
      __builtin_amdgcn_s_setprio(1);
#pragma unroll
      for (int mi = 0; mi < 8; ++mi) {
        acc[mi][0] = __builtin_amdgcn_mfma_f32_16x16x32_bf16(af[mi], bfr[0], acc[mi][0], 0, 0, 0);
        acc[mi][1] = __builtin_amdgcn_mfma_f32_16x16x32_bf16(af[mi], bfr[1], acc[mi][1], 0, 0, 0);
      }
      __builtin_amdgcn_s_setprio(0);
      __builtin_amdgcn_s_barrier();
    }
    // ===== phase 4: kk1, ni{2,3} =====
    {
      bfr[0] = *(const bf16x8*)(lds + sb + 8192 + boff + 1024);
      bfr[1] = *(const bf16x8*)(lds + sb + 8192 + boff + 1536);
      gload16(srcB + 32,          lds + db + 8192 + 16384 + sstage);  // stage B-kk1(tile v+1)
      gload16(srcB + 32 + brstep, lds + db + 8192 + 16384 + sstage + 4096);
      asm volatile("s_waitcnt vmcnt(4)" ::: "memory");      // tile v+1 kk0 slabs landed
      __builtin_amdgcn_s_barrier();
      asm volatile("s_waitcnt lgkmcnt(0)" ::: "memory");
      __builtin_amdgcn_s_setprio(1);
#pragma unroll
      for (int mi = 0; mi < 8; ++mi) {
        acc[mi][2] = __builtin_amdgcn_mfma_f32_16x16x32_bf16(af[mi], bfr[0], acc[mi][2], 0, 0, 0);
        acc[mi][3] = __builtin_amdgcn_mfma_f32_16x16x32_bf16(af[mi], bfr[1], acc[mi][3], 0, 0, 0);
      }
      __builtin_amdgcn_s_setprio(0);
      __builtin_amdgcn_s_barrier();
    }
  }

  // ---- epilogue
  const int fq = lane >> 4;
  const int crow = bm * 256 + wm * 128;
  const int ccol = bn * 256 + wn * 64 + fr;
#pragma unroll
  for (int mi = 0; mi < 8; ++mi) {
#pragma unroll
    for (int ni = 0; ni < 4; ++ni) {
#pragma unroll
      for (int ii = 0; ii < 4; ++ii) {
        const int r = crow + mi * 16 + fq * 4 + ii;
        const int c = ccol + ni * 16;
        const size_t idx = (size_t)r * ldc + c;
        float vv = acc[mi][ni][ii];
        if (EPI == 0) {
          ((float*)Cout)[idx] = vv;
        } else if (EPI == 1) {
          ((unsigned short*)Cout)[idx] = f2bf(vv);
        } else {
          ((unsigned short*)Cout)[idx] = f2bf(__expf(vv + eoff));
        }
      }
    }
  }
}

// ---------- dot[b,h,t] = sum_d qp[b,t,h*128+d] * kp[...] ----------
__global__ void dot_kernel(const unsigned short* __restrict__ qp,
                           const unsigned short* __restrict__ kp,
                           float* __restrict__ dotb) {
  int bid = blockIdx.x;            // (b*H + h)*T + t
  int t = bid % Tc;
  int bh = bid / Tc;
  int b = bh / Hc, h = bh % Hc;
  int d = threadIdx.x;             // 0..127
  size_t idx = ((size_t)(b * Tc + t)) * Dc + h * HDc + d;
  float p = bf2f(qp[idx]) * bf2f(kp[idx]);
#pragma unroll
  for (int s = 32; s; s >>= 1) p += __shfl_down(p, s);
  __shared__ float part[2];
  int lane = threadIdx.x & 63, wv = threadIdx.x >> 6;
  if (lane == 0) part[wv] = p;
  __syncthreads();
  if (threadIdx.x == 0) dotb[bid] = part[0] + part[1];
}

// ---------- chunked scan: pass 1 (per-chunk sums) ----------
__global__ void scan_chunks(const float* __restrict__ dotb,
                            const unsigned short* __restrict__ v,
                            float* __restrict__ chks) {
  int bid = blockIdx.x;            // bh*NCHUNK + c
  int c = bid % NCHUNK, bh = bid / NCHUNK;
  int b = bh / Hc, h = bh % Hc;
  int d = threadIdx.x;
  const float* dp = dotb + (size_t)bh * Tc + c * CHUNK;
  const unsigned short* vp = v + ((size_t)(b * Tc + c * CHUNK)) * Dc + h * HDc + d;
  float acc = 0.f;
  for (int t = 0; t < CHUNK; ++t)
    acc += dp[t] * bf2f(vp[(size_t)t * Dc]);
  chks[(size_t)bid * HDc + d] = acc;
}

// ---------- chunked scan: pass 2 (exclusive scan of chunk sums) ----------
__global__ void scan_offsets(float* __restrict__ chks) {
  int bh = blockIdx.x;
  int d = threadIdx.x;
  float run = 0.f;
  for (int c = 0; c < NCHUNK; ++c) {
    size_t idx = ((size_t)bh * NCHUNK + c) * HDc + d;
    float tmp = chks[idx];
    chks[idx] = run;
    run += tmp;
  }
}

// ---------- chunked scan: pass 3 (final prefix + divide by kp, bf16 out) ----------
__global__ void scan_final(const float* __restrict__ dotb,
                           const unsigned short* __restrict__ v,
                           const unsigned short* __restrict__ kp,
                           const float* __restrict__ chks,
                           unsigned short* __restrict__ attn) {
  int bid = blockIdx.x;
  int c = bid % NCHUNK, bh = bid / NCHUNK;
  int b = bh / Hc, h = bh % Hc;
  int d = threadIdx.x;
  const float* dp = dotb + (size_t)bh * Tc + c * CHUNK;
  size_t base = ((size_t)(b * Tc + c * CHUNK)) * Dc + h * HDc + d;
  float acc = chks[(size_t)bid * HDc + d];
  for (int t = 0; t < CHUNK; ++t) {
    size_t idx = base + (size_t)t * Dc;
    acc += dp[t] * bf2f(v[idx]);
    attn[idx] = f2bf(acc / bf2f(kp[idx]));
  }
}

// ---------- launch ----------
extern "C" void kernel_launch(void* const* d_in, const int* in_sizes, int n_in,
                              void* d_out, int out_size, void* d_ws, size_t ws_size,
                              hipStream_t stream) {
  const float* hs = (const float*)d_in[0];
  const float* Wq = (const float*)d_in[1];
  const float* Wk = (const float*)d_in[2];
  const float* Wv = (const float*)d_in[3];
  const float* Wo = (const float*)d_in[4];
  const float* Fq = (const float*)d_in[5];
  const float* Fk = (const float*)d_in[6];
  float* out = (float*)d_out;

  const size_t MD = (size_t)Mrows * Dc;  // 16,777,216
  const size_t DD = (size_t)Dc * Dc;     // 4,194,304

  char* w = (char*)d_ws;
  size_t off = 0;
  auto take = [&](size_t bytes) -> void* {
    void* r = w + off;
    off += (bytes + 255) & ~(size_t)255;
    return r;
  };

  unsigned short* hs_bf = (unsigned short*)take(MD * 2);  // later reused as Qp
  unsigned short* wtq  = (unsigned short*)take(DD * 2);
  unsigned short* wtk  = (unsigned short*)take(DD * 2);
  unsigned short* wtv  = (unsigned short*)take(DD * 2);
  unsigned short* wto  = (unsigned short*)take(DD * 2);
  unsigned short* wtfq = (unsigned short*)take(DD * 2);
  unsigned short* wtfk = (unsigned short*)take(DD * 2);
  unsigned short* Qbf  = (unsigned short*)take(MD * 2);   // later reused as Kp
  unsigned short* Kbf  = (unsigned short*)take(MD * 2);   // later reused as attn
  unsigned short* Vbf  = (unsigned short*)take(MD * 2);
  float* dotb = (float*)take((size_t)Bc * Hc * Tc * 4);
  float* chks = (float*)take((size_t)Bc * Hc * NCHUNK * HDc * 4);

  // aliases (stream-ordered reuse)
  unsigned short* Qp = hs_bf;
  unsigned short* Kp = Qbf;
  unsigned short* attnbf = Kbf;

  const float OFF = (float)(-0.5 * log(2048.0) + 1e-6);

  // allow 128 KiB dynamic LDS (defensive; ignore errors)
  (void)hipFuncSetAttribute((const void*)gemm256<0>, hipFuncAttributeMaxDynamicSharedMemorySize, 131072);
  (void)hipFuncSetAttribute((const void*)gemm256<1>, hipFuncAttributeMaxDynamicSharedMemorySize, 131072);
  (void)hipFuncSetAttribute((const void*)gemm256<2>, hipFuncAttributeMaxDynamicSharedMemorySize, 131072);

  // 1) convert activations
  cvt_bf16<<<(int)(MD / 1024), 256, 0, stream>>>(hs, hs_bf);

  // 2) transpose+convert weights
  dim3 tg(Dc / 32, Dc / 32);
  transpose_cvt<<<tg, 256, 0, stream>>>(Wq, wtq);
  transpose_cvt<<<tg, 256, 0, stream>>>(Wk, wtk);
  transpose_cvt<<<tg, 256, 0, stream>>>(Wv, wtv);
  transpose_cvt<<<tg, 256, 0, stream>>>(Wo, wto);
  transpose_cvt<<<tg, 256, 0, stream>>>(Fq, wtfq);
  transpose_cvt<<<tg, 256, 0, stream>>>(Fk, wtfk);

  const int gblocks = (Mrows / 256) * (Dc / 256);  // 256

  // 3) Q, K, V projections (bf16 out)
  gemm256<1><<<gblocks, 512, 131072, stream>>>(hs_bf, wtq, Qbf, Mrows, Dc, Dc, Dc, 0.f);
  gemm256<1><<<gblocks, 512, 131072, stream>>>(hs_bf, wtk, Kbf, Mrows, Dc, Dc, Dc, 0.f);
  gemm256<1><<<gblocks, 512, 131072, stream>>>(hs_bf, wtv, Vbf, Mrows, Dc, Dc, Dc, 0.f);

  // 4) feature maps with fused exp epilogue
  gemm256<2><<<gblocks, 512, 131072, stream>>>(Qbf, wtfq, Qp, Mrows, Dc, Dc, Dc, OFF);
  gemm256<2><<<gblocks, 512, 131072, stream>>>(Kbf, wtfk, Kp, Mrows, Dc, Dc, Dc, OFF);

  // 5) per-position dot over each head
  dot_kernel<<<Bc * Hc * Tc, 128, 0, stream>>>(Qp, Kp, dotb);

  // 6) chunked causal cumsum + divide, write bf16 attn (merged layout)
  scan_chunks<<<Bc * Hc * NCHUNK, 128, 0, stream>>>(dotb, Vbf, chks);
  scan_offsets<<<Bc * Hc, 128, 0, stream>>>(chks);
  scan_final<<<Bc * Hc * NCHUNK, 128, 0, stream>>>(dotb, Vbf, Kp, chks, attnbf);

  // 7) output projection (fp32 out)
  gemm256<0><<<gblocks, 512, 131072, stream>>>(attnbf, wto, out, Mrows, Dc, Dc, Dc, 0.f);
}

// Round 3
// 522.120 us; speedup vs baseline: 1.5237x; 1.0681x over previous
//
#include <hip/hip_runtime.h>
#include <hip/hip_bf16.h>
#include <cmath>

// Problem constants
constexpr int Bc = 2, Tc = 4096, Dc = 2048, Hc = 16, HDc = 128;
constexpr int Mrows = Bc * Tc;            // 8192
constexpr int NCHUNK = 32, CHUNK = 128;   // T = NCHUNK * CHUNK

// ---------- small helpers ----------
__device__ __forceinline__ unsigned short f2bf(float x) {
  union { float f; unsigned int u; } v; v.f = x;
  unsigned int r = v.u + 0x7FFFu + ((v.u >> 16) & 1u);  // RNE
  return (unsigned short)(r >> 16);
}
__device__ __forceinline__ float bf2f(unsigned short u) {
  union { unsigned int i; float f; } v; v.i = ((unsigned int)u) << 16;
  return v.f;
}

typedef __attribute__((ext_vector_type(8))) short bf16x8;
typedef __attribute__((ext_vector_type(4))) float f32x4;

__device__ __forceinline__ void gload16(const unsigned short* g, unsigned short* l) {
  __builtin_amdgcn_global_load_lds(
      (const __attribute__((address_space(1))) void*)(const void*)g,
      (__attribute__((address_space(3))) void*)(void*)l,
      16, 0, 0);
}

// ---------- fp32 -> bf16 convert (vectorized) ----------
__global__ void cvt_bf16(const float* __restrict__ in, unsigned short* __restrict__ outp) {
  size_t i = ((size_t)blockIdx.x * 256 + threadIdx.x) * 4;
  float4 f = *(const float4*)(in + i);
  ushort4 u;
  u.x = f2bf(f.x); u.y = f2bf(f.y); u.z = f2bf(f.z); u.w = f2bf(f.w);
  *(ushort4*)(outp + i) = u;
}

// ---------- W [K][N] fp32 -> Wt [N][K] bf16 ----------
__global__ void transpose_cvt(const float* __restrict__ W, unsigned short* __restrict__ Wt) {
  __shared__ float tile[32][33];
  int n0 = blockIdx.x * 32, k0 = blockIdx.y * 32;
  int tx = threadIdx.x & 31, ty = threadIdx.x >> 5;  // ty: 0..7
#pragma unroll
  for (int i = 0; i < 4; ++i)
    tile[ty + 8 * i][tx] = W[(size_t)(k0 + ty + 8 * i) * Dc + n0 + tx];
  __syncthreads();
#pragma unroll
  for (int i = 0; i < 4; ++i)
    Wt[(size_t)(n0 + ty + 8 * i) * Dc + k0 + tx] = f2bf(tile[tx][ty + 8 * i]);
}

// ============================================================================
// 256x256 8-phase GEMM: C[M,N] = A[M,K](bf16, lda) * Bt[N,K](bf16)^T
// K hardcoded 2048. 8 waves (2M x 4N), LDS 128 KiB (2 dbuf x (A,B) x 2 K-half
// slabs of [256][32] bf16). Counted vmcnt(4), setprio around MFMA clusters.
// LDS bank-conflict fix: element-col XOR swizzle c' = c ^ ((row&6)<<2),
// applied on the GLOBAL SOURCE for staging (LDS dest stays linear, as
// global_load_lds requires) and folded into the per-lane fragment offsets.
// EPI: 0 = fp32 store, 1 = bf16 store, 2 = bf16(exp(x + eoff))
// ============================================================================
template <int EPI>
__global__ __launch_bounds__(512, 2) void gemm256(
    const unsigned short* __restrict__ A,
    const unsigned short* __restrict__ Bt,
    void* __restrict__ Cout,
    int M, int N, int lda, int ldc, float eoff) {
  constexpr int K = 2048;
  constexpr int NT = K / 64;  // 32 K-tiles
  extern __shared__ unsigned short lds[];  // 65536 ushorts = 128 KiB

  const int tid = threadIdx.x;
  const int lane = tid & 63;
  const int wave = tid >> 6;   // 0..7
  const int wm = wave >> 2;    // 0..1
  const int wn = wave & 3;     // 0..3

  const int nbn = N >> 8;
  const int nwg = (M >> 8) * nbn;
  const int bidx = (int)blockIdx.x;
  const int wgid = (bidx & 7) * (nwg >> 3) + (bidx >> 3);  // XCD swizzle (nwg%8==0)
  const int bm = wgid / nbn;
  const int bn = wgid % nbn;

  // ---- staging addressing: one slab = 256 rows x 32 bf16 (64B rows), 2 gloads
  const int srow = tid >> 2;                  // 0..127
  const int scolL = (tid & 3) << 3;           // linear LDS col (elems): 0,8,16,24
  const int scolG = scolL ^ ((srow & 6) << 2);  // pre-swizzled global source col
  const unsigned short* gA = A + (size_t)(bm * 256 + srow) * lda + scolG;
  const unsigned short* gB = Bt + (size_t)(bn * 256 + srow) * K + scolG;
  const int sstage = srow * 32 + scolL;         // LDS elem offset (linear dest)
  const size_t arstep = (size_t)128 * lda;      // +128 rows (j=1)
  const size_t brstep = (size_t)128 * K;

  // ---- fragment read offsets (within a slab), swizzle folded per-lane
  const int fr = lane & 15;
  const int fko = ((lane >> 4) << 3) ^ ((lane & 6) << 2);  // swizzled k-col
  const int aoff = (wm * 128 + fr) * 32 + fko;            // + mi*512
  const int boff = 16384 + (wn * 64 + fr) * 32 + fko;     // + ni*512 (B at +16384)

  f32x4 acc[8][4] = {};
  bf16x8 af[8];
  bf16x8 bfr[2];

  // ---- prologue: stage tile 0 into buf0, order [A-kk0, B-kk0, A-kk1, B-kk1]
  {
    const unsigned short* sA = gA;
    const unsigned short* sB = gB;
    gload16(sA,          lds + sstage);
    gload16(sA + arstep, lds + sstage + 4096);
    gload16(sB,          lds + 16384 + sstage);
    gload16(sB + brstep, lds + 16384 + sstage + 4096);
    gload16(sA + 32,          lds + 8192 + sstage);
    gload16(sA + 32 + arstep, lds + 8192 + sstage + 4096);
    gload16(sB + 32,          lds + 8192 + 16384 + sstage);
    gload16(sB + 32 + brstep, lds + 8192 + 16384 + sstage + 4096);
  }
  asm volatile("s_waitcnt vmcnt(4)" ::: "memory");
  __builtin_amdgcn_s_barrier();

  for (int v = 0; v < NT; ++v) {
    const int b = v & 1;
    const int tn = (v + 1) & (NT - 1);            // wrap-stage: harmless reload of tile 0
    const int sb = b * 32768;                      // read buffer base
    const int db = (b ^ 1) * 32768;                // stage (write) buffer base
    const unsigned short* srcA = gA + tn * 64;
    const unsigned short* srcB = gB + tn * 64;

    // ===== phase 1: kk0, ni{0,1} =====
    {
#pragma unroll
      for (int mi = 0; mi < 8; ++mi)
        af[mi] = *(const bf16x8*)(lds + sb + aoff + mi * 512);
      bfr[0] = *(const bf16x8*)(lds + sb + boff);
      bfr[1] = *(const bf16x8*)(lds + sb + boff + 512);
      gload16(srcA,          lds + db + sstage);            // stage A-kk0(tile v+1)
      gload16(srcA + arstep, lds + db + sstage + 4096);
      __builtin_amdgcn_s_barrier();
      asm volatile("s_waitcnt lgkmcnt(0)" ::: "memory");
      __builtin_amdgcn_s_setprio(1);
#pragma unroll
      for (int mi = 0; mi < 8; ++mi) {
        acc[mi][0] = __builtin_amdgcn_mfma_f32_16x16x32_bf16(af[mi], bfr[0], acc[mi][0], 0, 0, 0);
        acc[mi][1] = __builtin_amdgcn_mfma_f32_16x16x32_bf16(af[mi], bfr[1], acc[mi][1], 0, 0, 0);
      }
      __builtin_amdgcn_s_setprio(0);
      __builtin_amdgcn_s_barrier();
    }
    // ===== phase 2: kk0, ni{2,3} (A frags reused) =====
    {
      bfr[0] = *(const bf16x8*)(lds + sb + boff + 1024);
      bfr[1] = *(const bf16x8*)(lds + sb + boff + 1536);
      gload16(srcB,          lds + db + 16384 + sstage);    // stage B-kk0(tile v+1)
      gload16(srcB + brstep, lds + db + 16384 + sstage + 4096);
      asm volatile("s_waitcnt vmcnt(4)" ::: "memory");      // tile v kk1 slabs landed
      __builtin_amdgcn_s_barrier();
      asm volatile("s_waitcnt lgkmcnt(0)" ::: "memory");
      __builtin_amdgcn_s_setprio(1);
#pragma unroll
      for (int mi = 0; mi < 8; ++mi) {
        acc[mi][2] = __builtin_amdgcn_mfma_f32_16x16x32_bf16(af[mi], bfr[0], acc[mi][2], 0, 0, 0);
        acc[mi][3] = __builtin_amdgcn_mfma_f32_16x16x32_bf16(af[mi], bfr[1], acc[mi][3], 0, 0, 0);
      }
      __builtin_amdgcn_s_setprio(0);
      __builtin_amdgcn_s_barrier();
    }
    // ===== phase 3: kk1, ni{0,1} =====
    {
#pragma unroll
      for (int mi = 0; mi < 8; ++mi)
        af[mi] = *(const bf16x8*)(lds + sb + 8192 + aoff + mi * 512);
      bfr[0] = *(const bf16x8*)(lds + sb + 8192 + boff);
      bfr[1] = *(const bf16x8*)(lds + sb + 8192 + boff + 512);
      gload16(srcA + 32,          lds + db + 8192 + sstage);  // stage A-kk1(tile v+1)
      gload16(srcA + 32 + arstep, lds + db + 8192 + sstage + 4096);
      __builtin_amdgcn_s_barrier();
      asm volatile("s_waitcnt lgkmcnt(0)" ::: "memory");
      __builtin_amdgcn_s_setprio(1);
#pragma unroll
      for (int mi = 0; mi < 8; ++mi) {
        acc[mi][0] = __builtin_amdgcn_mfma_f32_16x16x32_bf16(af[mi], bfr[0], acc[mi][0], 0, 0, 0);
        acc[mi][1] = __builtin_amdgcn_mfma_f32_16x16x32_bf16(af[mi], bfr[1], acc[mi][1], 0, 0, 0);
      }
      __builtin_amdgcn_s_setprio(0);
      __builtin_amdgcn_s_barrier();
    }
    // ===== phase 4: kk1, ni{2,3} =====
    {
      bfr[0] = *(const bf16x8*)(lds + sb + 8192 + boff + 1024);
      bfr[1] = *(const bf16x8*)(lds + sb + 8192 + boff + 1536);
      gload16(srcB + 32,          lds + db + 8192 + 16384 + sstage);  // stage B-kk1(tile v+1)
      gload16(srcB + 32 + brstep, lds + db + 8192 + 16384 + sstage + 4096);
      asm volatile("s_waitcnt vmcnt(4)" ::: "memory");      // tile v+1 kk0 slabs landed
      __builtin_amdgcn_s_barrier();
      asm volatile("s_waitcnt lgkmcnt(0)" ::: "memory");
      __builtin_amdgcn_s_setprio(1);
#pragma unroll
      for (int mi = 0; mi < 8; ++mi) {
        acc[mi][2] = __builtin_amdgcn_mfma_f32_16x16x32_bf16(af[mi], bfr[0], acc[mi][2], 0, 0, 0);
        acc[mi][3] = __builtin_amdgcn_mfma_f32_16x16x32_bf16(af[mi], bfr[1], acc[mi][3], 0, 0, 0);
      }
      __builtin_amdgcn_s_setprio(0);
      __builtin_amdgcn_s_barrier();
    }
  }

  // ---- epilogue
  const int fq = lane >> 4;
  const int crow = bm * 256 + wm * 128;
  const int ccol = bn * 256 + wn * 64 + fr;
#pragma unroll
  for (int mi = 0; mi < 8; ++mi) {
#pragma unroll
    for (int ni = 0; ni < 4; ++ni) {
#pragma unroll
      for (int ii = 0; ii < 4; ++ii) {
        const int r = crow + mi * 16 + fq * 4 + ii;
        const int c = ccol + ni * 16;
        const size_t idx = (size_t)r * ldc + c;
        float vv = acc[mi][ni][ii];
        if (EPI == 0) {
          ((float*)Cout)[idx] = vv;
        } else if (EPI == 1) {
          ((unsigned short*)Cout)[idx] = f2bf(vv);
        } else {
          ((unsigned short*)Cout)[idx] = f2bf(__expf(vv + eoff));
        }
      }
    }
  }
}

// ---------- dot[b,h,t] = sum_d qp[.]*kp[.] ----------
// One quarter-wave (16 lanes) per t; each wave covers 4 consecutive t per
// iteration with fully-coalesced bf16x8 loads (1 KB per wave per operand).
__global__ void dot_kernel(const unsigned short* __restrict__ qp,
                           const unsigned short* __restrict__ kp,
                           float* __restrict__ dotb) {
  const int BHT = Bc * Hc * Tc;  // 131072
  const int lane = threadIdx.x & 63;
  const int qw = lane >> 4;      // quarter-wave index 0..3
  const int j = lane & 15;       // 8-elem group within row
  const int gw = (blockIdx.x * blockDim.x + threadIdx.x) >> 6;  // global wave
  const int nw = (gridDim.x * blockDim.x) >> 6;

  for (int flat = gw * 4 + qw; flat < BHT; flat += nw * 4) {
    const int bh = flat >> 12;        // /T
    const int t = flat & (Tc - 1);
    const int b = bh >> 4, h = bh & 15;
    const size_t base = ((size_t)(b * Tc + t)) * Dc + h * HDc + j * 8;
    bf16x8 q = *(const bf16x8*)(qp + base);
    bf16x8 k = *(const bf16x8*)(kp + base);
    float p = 0.f;
#pragma unroll
    for (int i = 0; i < 8; ++i)
      p += bf2f((unsigned short)q[i]) * bf2f((unsigned short)k[i]);
#pragma unroll
    for (int m = 8; m; m >>= 1) p += __shfl_xor(p, m);
    if (j == 0) dotb[flat] = p;
  }
}

// ---------- chunked scan: pass 1 (per-chunk sums) ----------
__global__ void scan_chunks(const float* __restrict__ dotb,
                            const unsigned short* __restrict__ v,
                            float* __restrict__ chks) {
  int bid = blockIdx.x;            // bh*NCHUNK + c
  int c = bid % NCHUNK, bh = bid / NCHUNK;
  int b = bh / Hc, h = bh % Hc;
  int d = threadIdx.x;
  const float* dp = dotb + (size_t)bh * Tc + c * CHUNK;
  const unsigned short* vp = v + ((size_t)(b * Tc + c * CHUNK)) * Dc + h * HDc + d;
  float acc = 0.f;
  for (int t = 0; t < CHUNK; ++t)
    acc += dp[t] * bf2f(vp[(size_t)t * Dc]);
  chks[(size_t)bid * HDc + d] = acc;
}

// ---------- chunked scan: pass 2 (exclusive scan of chunk sums) ----------
__global__ void scan_offsets(float* __restrict__ chks) {
  int bh = blockIdx.x;
  int d = threadIdx.x;
  float run = 0.f;
  for (int c = 0; c < NCHUNK; ++c) {
    size_t idx = ((size_t)bh * NCHUNK + c) * HDc + d;
    float tmp = chks[idx];
    chks[idx] = run;
    run += tmp;
  }
}

// ---------- chunked scan: pass 3 (final prefix + divide by kp, bf16 out) ----------
__global__ void scan_final(const float* __restrict__ dotb,
                           const unsigned short* __restrict__ v,
                           const unsigned short* __restrict__ kp,
                           const float* __restrict__ chks,
                           unsigned short* __restrict__ attn) {
  int bid = blockIdx.x;
  int c = bid % NCHUNK, bh = bid / NCHUNK;
  int b = bh / Hc, h = bh % Hc;
  int d = threadIdx.x;
  const float* dp = dotb + (size_t)bh * Tc + c * CHUNK;
  size_t base = ((size_t)(b * Tc + c * CHUNK)) * Dc + h * HDc + d;
  float acc = chks[(size_t)bid * HDc + d];
  for (int t = 0; t < CHUNK; ++t) {
    size_t idx = base + (size_t)t * Dc;
    acc += dp[t] * bf2f(v[idx]);
    attn[idx] = f2bf(acc / bf2f(kp[idx]));
  }
}

// ---------- launch ----------
extern "C" void kernel_launch(void* const* d_in, const int* in_sizes, int n_in,
                              void* d_out, int out_size, void* d_ws, size_t ws_size,
                              hipStream_t stream) {
  const float* hs = (const float*)d_in[0];
  const float* Wq = (const float*)d_in[1];
  const float* Wk = (const float*)d_in[2];
  const float* Wv = (const float*)d_in[3];
  const float* Wo = (const float*)d_in[4];
  const float* Fq = (const float*)d_in[5];
  const float* Fk = (const float*)d_in[6];
  float* out = (float*)d_out;

  const size_t MD = (size_t)Mrows * Dc;  // 16,777,216
  const size_t DD = (size_t)Dc * Dc;     // 4,194,304

  char* w = (char*)d_ws;
  size_t off = 0;
  auto take = [&](size_t bytes) -> void* {
    void* r = w + off;
    off += (bytes + 255) & ~(size_t)255;
    return r;
  };

  unsigned short* hs_bf = (unsigned short*)take(MD * 2);  // later reused as Qp
  unsigned short* wtq  = (unsigned short*)take(DD * 2);
  unsigned short* wtk  = (unsigned short*)take(DD * 2);
  unsigned short* wtv  = (unsigned short*)take(DD * 2);
  unsigned short* wto  = (unsigned short*)take(DD * 2);
  unsigned short* wtfq = (unsigned short*)take(DD * 2);
  unsigned short* wtfk = (unsigned short*)take(DD * 2);
  unsigned short* Qbf  = (unsigned short*)take(MD * 2);   // later reused as Kp
  unsigned short* Kbf  = (unsigned short*)take(MD * 2);   // later reused as attn
  unsigned short* Vbf  = (unsigned short*)take(MD * 2);
  float* dotb = (float*)take((size_t)Bc * Hc * Tc * 4);
  float* chks = (float*)take((size_t)Bc * Hc * NCHUNK * HDc * 4);

  // aliases (stream-ordered reuse)
  unsigned short* Qp = hs_bf;
  unsigned short* Kp = Qbf;
  unsigned short* attnbf = Kbf;

  const float OFF = (float)(-0.5 * log(2048.0) + 1e-6);

  // allow 128 KiB dynamic LDS (defensive; ignore errors)
  (void)hipFuncSetAttribute((const void*)gemm256<0>, hipFuncAttributeMaxDynamicSharedMemorySize, 131072);
  (void)hipFuncSetAttribute((const void*)gemm256<1>, hipFuncAttributeMaxDynamicSharedMemorySize, 131072);
  (void)hipFuncSetAttribute((const void*)gemm256<2>, hipFuncAttributeMaxDynamicSharedMemorySize, 131072);

  // 1) convert activations
  cvt_bf16<<<(int)(MD / 1024), 256, 0, stream>>>(hs, hs_bf);

  // 2) transpose+convert weights
  dim3 tg(Dc / 32, Dc / 32);
  transpose_cvt<<<tg, 256, 0, stream>>>(Wq, wtq);
  transpose_cvt<<<tg, 256, 0, stream>>>(Wk, wtk);
  transpose_cvt<<<tg, 256, 0, stream>>>(Wv, wtv);
  transpose_cvt<<<tg, 256, 0, stream>>>(Wo, wto);
  transpose_cvt<<<tg, 256, 0, stream>>>(Fq, wtfq);
  transpose_cvt<<<tg, 256, 0, stream>>>(Fk, wtfk);

  const int gblocks = (Mrows / 256) * (Dc / 256);  // 256

  // 3) Q, K, V projections (bf16 out)
  gemm256<1><<<gblocks, 512, 131072, stream>>>(hs_bf, wtq, Qbf, Mrows, Dc, Dc, Dc, 0.f);
  gemm256<1><<<gblocks, 512, 131072, stream>>>(hs_bf, wtk, Kbf, Mrows, Dc, Dc, Dc, 0.f);
  gemm256<1><<<gblocks, 512, 131072, stream>>>(hs_bf, wtv, Vbf, Mrows, Dc, Dc, Dc, 0.f);

  // 4) feature maps with fused exp epilogue
  gemm256<2><<<gblocks, 512, 131072, stream>>>(Qbf, wtfq, Qp, Mrows, Dc, Dc, Dc, OFF);
  gemm256<2><<<gblocks, 512, 131072, stream>>>(Kbf, wtfk, Kp, Mrows, Dc, Dc, Dc, OFF);

  // 5) per-position dot over each head
  dot_kernel<<<1024, 256, 0, stream>>>(Qp, Kp, dotb);

  // 6) chunked causal cumsum + divide, write bf16 attn (merged layout)
  scan_chunks<<<Bc * Hc * NCHUNK, 128, 0, stream>>>(dotb, Vbf, chks);
  scan_offsets<<<Bc * Hc, 128, 0, stream>>>(chks);
  scan_final<<<Bc * Hc * NCHUNK, 128, 0, stream>>>(dotb, Vbf, Kp, chks, attnbf);

  // 7) output projection (fp32 out)
  gemm256<0><<<gblocks, 512, 131072, stream>>>(attnbf, wto, out, Mrows, Dc, Dc, Dc, 0.f);
}

// Round 4
// 444.363 us; speedup vs baseline: 1.7904x; 1.1750x over previous
//
#include <hip/hip_runtime.h>
#include <hip/hip_bf16.h>
#include <cmath>

// Problem constants
constexpr int Bc = 2, Tc = 4096, Dc = 2048, Hc = 16, HDc = 128;
constexpr int Mrows = Bc * Tc;            // 8192
constexpr int NCHUNK = 32, CHUNK = 128;   // T = NCHUNK * CHUNK

// ---------- small helpers ----------
__device__ __forceinline__ unsigned short f2bf(float x) {
  union { float f; unsigned int u; } v; v.f = x;
  unsigned int r = v.u + 0x7FFFu + ((v.u >> 16) & 1u);  // RNE
  return (unsigned short)(r >> 16);
}
__device__ __forceinline__ float bf2f(unsigned short u) {
  union { unsigned int i; float f; } v; v.i = ((unsigned int)u) << 16;
  return v.f;
}

typedef __attribute__((ext_vector_type(8))) short bf16x8;
typedef __attribute__((ext_vector_type(4))) float f32x4;

__device__ __forceinline__ void gload16(const unsigned short* g, unsigned short* l) {
  __builtin_amdgcn_global_load_lds(
      (const __attribute__((address_space(1))) void*)(const void*)g,
      (__attribute__((address_space(3))) void*)(void*)l,
      16, 0, 0);
}

// ---------- fp32 -> bf16 convert (vectorized) ----------
__global__ void cvt_bf16(const float* __restrict__ in, unsigned short* __restrict__ outp) {
  size_t i = ((size_t)blockIdx.x * 256 + threadIdx.x) * 4;
  float4 f = *(const float4*)(in + i);
  ushort4 u;
  u.x = f2bf(f.x); u.y = f2bf(f.y); u.z = f2bf(f.z); u.w = f2bf(f.w);
  *(ushort4*)(outp + i) = u;
}

// ---------- W [K][N] fp32 -> Wt [N][K] bf16 ----------
__global__ void transpose_cvt(const float* __restrict__ W, unsigned short* __restrict__ Wt) {
  __shared__ float tile[32][33];
  int n0 = blockIdx.x * 32, k0 = blockIdx.y * 32;
  int tx = threadIdx.x & 31, ty = threadIdx.x >> 5;  // ty: 0..7
#pragma unroll
  for (int i = 0; i < 4; ++i)
    tile[ty + 8 * i][tx] = W[(size_t)(k0 + ty + 8 * i) * Dc + n0 + tx];
  __syncthreads();
#pragma unroll
  for (int i = 0; i < 4; ++i)
    Wt[(size_t)(n0 + ty + 8 * i) * Dc + k0 + tx] = f2bf(tile[tx][ty + 8 * i]);
}

// ============================================================================
// z-batched 128x128 GEMM (2 problems): C[M,N] = A[M,K] * Bt[N,K]^T, bf16 out.
// M=N=K=2048 hardcoded. XOR bank-conflict swizzle (source-side + read-side).
// Used for the weight-product precompute: Wqf^T = Fq^T * Wq^T, etc.
// ============================================================================
__global__ __launch_bounds__(256) void gemm_pair(
    const unsigned short* __restrict__ A0, const unsigned short* __restrict__ B0,
    unsigned short* __restrict__ C0,
    const unsigned short* __restrict__ A1, const unsigned short* __restrict__ B1,
    unsigned short* __restrict__ C1) {
  constexpr int K = 2048, N = 2048;
  constexpr int BK = 32;
  __shared__ __align__(16) unsigned short lds_a[128 * BK];
  __shared__ __align__(16) unsigned short lds_b[128 * BK];

  const unsigned short* A = blockIdx.y ? A1 : A0;
  const unsigned short* Bt = blockIdx.y ? B1 : B0;
  unsigned short* C = blockIdx.y ? C1 : C0;

  const int tid = threadIdx.x;
  const int wave = tid >> 6;
  const int lane = tid & 63;

  const int nbn = N / 128;       // 16
  const int nwg = (2048 / 128) * nbn;  // 256
  const int bid = blockIdx.x;
  const int wgid = (bid & 7) * (nwg >> 3) + (bid >> 3);
  const int bm = wgid / nbn;
  const int bn = wgid % nbn;

  const int wm = wave >> 1, wn = wave & 1;
  const int srow = tid >> 2;                    // 0..63
  const int scolL = (tid & 3) << 3;
  const int scolG = scolL ^ ((srow & 6) << 2);  // pre-swizzled source col

  const unsigned short* ga = A + (size_t)(bm * 128 + srow) * K + scolG;
  const unsigned short* gb = Bt + (size_t)(bn * 128 + srow) * K + scolG;
  const size_t rstep = (size_t)64 * K;

  f32x4 acc[4][4] = {};

  const int fr = lane & 15;
  const int fko = ((lane >> 4) << 3) ^ ((lane & 6) << 2);  // swizzled k-col

  for (int kt = 0; kt < K; kt += BK) {
    gload16(ga,         lds_a + wave * 512);
    gload16(ga + rstep, lds_a + 2048 + wave * 512);
    gload16(gb,         lds_b + wave * 512);
    gload16(gb + rstep, lds_b + 2048 + wave * 512);
    ga += BK; gb += BK;
    __syncthreads();

    bf16x8 af[4], bfr[4];
#pragma unroll
    for (int i = 0; i < 4; ++i) {
      af[i]  = *(const bf16x8*)(lds_a + (wm * 64 + i * 16 + fr) * BK + fko);
      bfr[i] = *(const bf16x8*)(lds_b + (wn * 64 + i * 16 + fr) * BK + fko);
    }
#pragma unroll
    for (int mi = 0; mi < 4; ++mi)
#pragma unroll
      for (int ni = 0; ni < 4; ++ni)
        acc[mi][ni] = __builtin_amdgcn_mfma_f32_16x16x32_bf16(af[mi], bfr[ni], acc[mi][ni], 0, 0, 0);
    __syncthreads();
  }

  const int fq = lane >> 4;
#pragma unroll
  for (int mi = 0; mi < 4; ++mi)
#pragma unroll
    for (int ni = 0; ni < 4; ++ni)
#pragma unroll
      for (int ii = 0; ii < 4; ++ii) {
        const int row = bm * 128 + wm * 64 + mi * 16 + fq * 4 + ii;
        const int col = bn * 128 + wn * 64 + ni * 16 + fr;
        C[(size_t)row * N + col] = f2bf(acc[mi][ni][ii]);
      }
}

// ============================================================================
// 256x256 8-phase GEMM: C[M,N] = A[M,K](bf16, lda) * Bt[N,K](bf16)^T
// K hardcoded 2048. 8 waves (2M x 4N), LDS 128 KiB, counted vmcnt(4), setprio.
// XOR swizzle: source-side for staging (LDS dest linear) + folded into reads.
// EPI: 0 = fp32 store, 1 = bf16 store, 2 = bf16(exp(x+eoff)),
//      3 = fused QKV: seg0->exp->Cout, seg1->exp->C1, seg2->plain->C2
//          (N=6144, each segment 2048 cols, ldc=2048)
// ============================================================================
template <int EPI>
__global__ __launch_bounds__(512, 2) void gemm256(
    const unsigned short* __restrict__ A,
    const unsigned short* __restrict__ Bt,
    void* __restrict__ Cout, void* __restrict__ C1, void* __restrict__ C2,
    int M, int N, int lda, int ldc, float eoff) {
  constexpr int K = 2048;
  constexpr int NT = K / 64;  // 32 K-tiles
  extern __shared__ unsigned short lds[];  // 65536 ushorts = 128 KiB

  const int tid = threadIdx.x;
  const int lane = tid & 63;
  const int wave = tid >> 6;   // 0..7
  const int wm = wave >> 2;    // 0..1
  const int wn = wave & 3;     // 0..3

  const int nbn = N >> 8;
  const int nwg = (M >> 8) * nbn;
  const int bidx = (int)blockIdx.x;
  const int wgid = (bidx & 7) * (nwg >> 3) + (bidx >> 3);  // XCD swizzle (nwg%8==0)
  const int bm = wgid / nbn;
  const int bn = wgid % nbn;

  // ---- staging addressing: one slab = 256 rows x 32 bf16 (64B rows), 2 gloads
  const int srow = tid >> 2;                  // 0..127
  const int scolL = (tid & 3) << 3;           // linear LDS col (elems)
  const int scolG = scolL ^ ((srow & 6) << 2);  // pre-swizzled global source col
  const unsigned short* gA = A + (size_t)(bm * 256 + srow) * lda + scolG;
  const unsigned short* gB = Bt + (size_t)(bn * 256 + srow) * K + scolG;
  const int sstage = srow * 32 + scolL;         // LDS elem offset (linear dest)
  const size_t arstep = (size_t)128 * lda;      // +128 rows (j=1)
  const size_t brstep = (size_t)128 * K;

  // ---- fragment read offsets (within a slab), swizzle folded per-lane
  const int fr = lane & 15;
  const int fko = ((lane >> 4) << 3) ^ ((lane & 6) << 2);  // swizzled k-col
  const int aoff = (wm * 128 + fr) * 32 + fko;            // + mi*512
  const int boff = 16384 + (wn * 64 + fr) * 32 + fko;     // + ni*512 (B at +16384)

  f32x4 acc[8][4] = {};
  bf16x8 af[8];
  bf16x8 bfr[2];

  // ---- prologue: stage tile 0 into buf0, order [A-kk0, B-kk0, A-kk1, B-kk1]
  {
    const unsigned short* sA = gA;
    const unsigned short* sB = gB;
    gload16(sA,          lds + sstage);
    gload16(sA + arstep, lds + sstage + 4096);
    gload16(sB,          lds + 16384 + sstage);
    gload16(sB + brstep, lds + 16384 + sstage + 4096);
    gload16(sA + 32,          lds + 8192 + sstage);
    gload16(sA + 32 + arstep, lds + 8192 + sstage + 4096);
    gload16(sB + 32,          lds + 8192 + 16384 + sstage);
    gload16(sB + 32 + brstep, lds + 8192 + 16384 + sstage + 4096);
  }
  asm volatile("s_waitcnt vmcnt(4)" ::: "memory");
  __builtin_amdgcn_s_barrier();

  for (int v = 0; v < NT; ++v) {
    const int b = v & 1;
    const int tn = (v + 1) & (NT - 1);            // wrap-stage: harmless reload of tile 0
    const int sb = b * 32768;                      // read buffer base
    const int db = (b ^ 1) * 32768;                // stage (write) buffer base
    const unsigned short* srcA = gA + tn * 64;
    const unsigned short* srcB = gB + tn * 64;

    // ===== phase 1: kk0, ni{0,1} =====
    {
#pragma unroll
      for (int mi = 0; mi < 8; ++mi)
        af[mi] = *(const bf16x8*)(lds + sb + aoff + mi * 512);
      bfr[0] = *(const bf16x8*)(lds + sb + boff);
      bfr[1] = *(const bf16x8*)(lds + sb + boff + 512);
      gload16(srcA,          lds + db + sstage);            // stage A-kk0(tile v+1)
      gload16(srcA + arstep, lds + db + sstage + 4096);
      __builtin_amdgcn_s_barrier();
      asm volatile("s_waitcnt lgkmcnt(0)" ::: "memory");
      __builtin_amdgcn_s_setprio(1);
#pragma unroll
      for (int mi = 0; mi < 8; ++mi) {
        acc[mi][0] = __builtin_amdgcn_mfma_f32_16x16x32_bf16(af[mi], bfr[0], acc[mi][0], 0, 0, 0);
        acc[mi][1] = __builtin_amdgcn_mfma_f32_16x16x32_bf16(af[mi], bfr[1], acc[mi][1], 0, 0, 0);
      }
      __builtin_amdgcn_s_setprio(0);
      __builtin_amdgcn_s_barrier();
    }
    // ===== phase 2: kk0, ni{2,3} (A frags reused) =====
    {
      bfr[0] = *(const bf16x8*)(lds + sb + boff + 1024);
      bfr[1] = *(const bf16x8*)(lds + sb + boff + 1536);
      gload16(srcB,          lds + db + 16384 + sstage);    // stage B-kk0(tile v+1)
      gload16(srcB + brstep, lds + db + 16384 + sstage + 4096);
      asm volatile("s_waitcnt vmcnt(4)" ::: "memory");      // tile v kk1 slabs landed
      __builtin_amdgcn_s_barrier();
      asm volatile("s_waitcnt lgkmcnt(0)" ::: "memory");
      __builtin_amdgcn_s_setprio(1);
#pragma unroll
      for (int mi = 0; mi < 8; ++mi) {
        acc[mi][2] = __builtin_amdgcn_mfma_f32_16x16x32_bf16(af[mi], bfr[0], acc[mi][2], 0, 0, 0);
        acc[mi][3] = __builtin_amdgcn_mfma_f32_16x16x32_bf16(af[mi], bfr[1], acc[mi][3], 0, 0, 0);
      }
      __builtin_amdgcn_s_setprio(0);
      __builtin_amdgcn_s_barrier();
    }
    // ===== phase 3: kk1, ni{0,1} =====
    {
#pragma unroll
      for (int mi = 0; mi < 8; ++mi)
        af[mi] = *(const bf16x8*)(lds + sb + 8192 + aoff + mi * 512);
      bfr[0] = *(const bf16x8*)(lds + sb + 8192 + boff);
      bfr[1] = *(const bf16x8*)(lds + sb + 8192 + boff + 512);
      gload16(srcA + 32,          lds + db + 8192 + sstage);  // stage A-kk1(tile v+1)
      gload16(srcA + 32 + arstep, lds + db + 8192 + sstage + 4096);
      __builtin_amdgcn_s_barrier();
      asm volatile("s_waitcnt lgkmcnt(0)" ::: "memory");
      __builtin_amdgcn_s_setprio(1);
#pragma unroll
      for (int mi = 0; mi < 8; ++mi) {
        acc[mi][0] = __builtin_amdgcn_mfma_f32_16x16x32_bf16(af[mi], bfr[0], acc[mi][0], 0, 0, 0);
        acc[mi][1] = __builtin_amdgcn_mfma_f32_16x16x32_bf16(af[mi], bfr[1], acc[mi][1], 0, 0, 0);
      }
      __builtin_amdgcn_s_setprio(0);
      __builtin_amdgcn_s_barrier();
    }
    // ===== phase 4: kk1, ni{2,3} =====
    {
      bfr[0] = *(const bf16x8*)(lds + sb + 8192 + boff + 1024);
      bfr[1] = *(const bf16x8*)(lds + sb + 8192 + boff + 1536);
      gload16(srcB + 32,          lds + db + 8192 + 16384 + sstage);  // stage B-kk1(tile v+1)
      gload16(srcB + 32 + brstep, lds + db + 8192 + 16384 + sstage + 4096);
      asm volatile("s_waitcnt vmcnt(4)" ::: "memory");      // tile v+1 kk0 slabs landed
      __builtin_amdgcn_s_barrier();
      asm volatile("s_waitcnt lgkmcnt(0)" ::: "memory");
      __builtin_amdgcn_s_setprio(1);
#pragma unroll
      for (int mi = 0; mi < 8; ++mi) {
        acc[mi][2] = __builtin_amdgcn_mfma_f32_16x16x32_bf16(af[mi], bfr[0], acc[mi][2], 0, 0, 0);
        acc[mi][3] = __builtin_amdgcn_mfma_f32_16x16x32_bf16(af[mi], bfr[1], acc[mi][3], 0, 0, 0);
      }
      __builtin_amdgcn_s_setprio(0);
      __builtin_amdgcn_s_barrier();
    }
  }

  // ---- epilogue
  const int fq = lane >> 4;
  const int crow = bm * 256 + wm * 128;
  if (EPI == 3) {
    const int seg = bn >> 3;  // 0:Q 1:K 2:V
    unsigned short* outp = (unsigned short*)(seg == 0 ? Cout : (seg == 1 ? C1 : C2));
    const int ccol = (bn & 7) * 256 + wn * 64 + fr;
#pragma unroll
    for (int mi = 0; mi < 8; ++mi)
#pragma unroll
      for (int ni = 0; ni < 4; ++ni)
#pragma unroll
        for (int ii = 0; ii < 4; ++ii) {
          const int r = crow + mi * 16 + fq * 4 + ii;
          const int c = ccol + ni * 16;
          float vv = acc[mi][ni][ii];
          if (seg < 2) vv = __expf(vv + eoff);
          outp[(size_t)r * ldc + c] = f2bf(vv);
        }
  } else {
    const int ccol = bn * 256 + wn * 64 + fr;
#pragma unroll
    for (int mi = 0; mi < 8; ++mi)
#pragma unroll
      for (int ni = 0; ni < 4; ++ni)
#pragma unroll
        for (int ii = 0; ii < 4; ++ii) {
          const int r = crow + mi * 16 + fq * 4 + ii;
          const int c = ccol + ni * 16;
          const size_t idx = (size_t)r * ldc + c;
          float vv = acc[mi][ni][ii];
          if (EPI == 0) {
            ((float*)Cout)[idx] = vv;
          } else if (EPI == 1) {
            ((unsigned short*)Cout)[idx] = f2bf(vv);
          } else {
            ((unsigned short*)Cout)[idx] = f2bf(__expf(vv + eoff));
          }
        }
  }
}

// ---------- dot[b,h,t] = sum_d qp[.]*kp[.] ----------
__global__ void dot_kernel(const unsigned short* __restrict__ qp,
                           const unsigned short* __restrict__ kp,
                           float* __restrict__ dotb) {
  const int BHT = Bc * Hc * Tc;  // 131072
  const int lane = threadIdx.x & 63;
  const int qw = lane >> 4;      // quarter-wave index 0..3
  const int j = lane & 15;       // 8-elem group within row
  const int gw = (blockIdx.x * blockDim.x + threadIdx.x) >> 6;  // global wave
  const int nw = (gridDim.x * blockDim.x) >> 6;

  for (int flat = gw * 4 + qw; flat < BHT; flat += nw * 4) {
    const int bh = flat >> 12;        // /T
    const int t = flat & (Tc - 1);
    const int b = bh >> 4, h = bh & 15;
    const size_t base = ((size_t)(b * Tc + t)) * Dc + h * HDc + j * 8;
    bf16x8 q = *(const bf16x8*)(qp + base);
    bf16x8 k = *(const bf16x8*)(kp + base);
    float p = 0.f;
#pragma unroll
    for (int i = 0; i < 8; ++i)
      p += bf2f((unsigned short)q[i]) * bf2f((unsigned short)k[i]);
#pragma unroll
    for (int m = 8; m; m >>= 1) p += __shfl_xor(p, m);
    if (j == 0) dotb[flat] = p;
  }
}

// ---------- chunked scan: pass 1 (per-chunk sums) ----------
__global__ void scan_chunks(const float* __restrict__ dotb,
                            const unsigned short* __restrict__ v,
                            float* __restrict__ chks) {
  int bid = blockIdx.x;            // bh*NCHUNK + c
  int c = bid % NCHUNK, bh = bid / NCHUNK;
  int b = bh / Hc, h = bh % Hc;
  int d = threadIdx.x;
  const float* dp = dotb + (size_t)bh * Tc + c * CHUNK;
  const unsigned short* vp = v + ((size_t)(b * Tc + c * CHUNK)) * Dc + h * HDc + d;
  float acc = 0.f;
  for (int t = 0; t < CHUNK; ++t)
    acc += dp[t] * bf2f(vp[(size_t)t * Dc]);
  chks[(size_t)bid * HDc + d] = acc;
}

// ---------- chunked scan: pass 2 (exclusive scan of chunk sums) ----------
__global__ void scan_offsets(float* __restrict__ chks) {
  int bh = blockIdx.x;
  int d = threadIdx.x;
  float run = 0.f;
  for (int c = 0; c < NCHUNK; ++c) {
    size_t idx = ((size_t)bh * NCHUNK + c) * HDc + d;
    float tmp = chks[idx];
    chks[idx] = run;
    run += tmp;
  }
}

// ---------- chunked scan: pass 3 (final prefix + divide by kp, bf16 out) ----------
__global__ void scan_final(const float* __restrict__ dotb,
                           const unsigned short* __restrict__ v,
                           const unsigned short* __restrict__ kp,
                           const float* __restrict__ chks,
                           unsigned short* __restrict__ attn) {
  int bid = blockIdx.x;
  int c = bid % NCHUNK, bh = bid / NCHUNK;
  int b = bh / Hc, h = bh % Hc;
  int d = threadIdx.x;
  const float* dp = dotb + (size_t)bh * Tc + c * CHUNK;
  size_t base = ((size_t)(b * Tc + c * CHUNK)) * Dc + h * HDc + d;
  float acc = chks[(size_t)bid * HDc + d];
  for (int t = 0; t < CHUNK; ++t) {
    size_t idx = base + (size_t)t * Dc;
    acc += dp[t] * bf2f(v[idx]);
    attn[idx] = f2bf(acc / bf2f(kp[idx]));
  }
}

// ---------- launch ----------
extern "C" void kernel_launch(void* const* d_in, const int* in_sizes, int n_in,
                              void* d_out, int out_size, void* d_ws, size_t ws_size,
                              hipStream_t stream) {
  const float* hs = (const float*)d_in[0];
  const float* Wq = (const float*)d_in[1];
  const float* Wk = (const float*)d_in[2];
  const float* Wv = (const float*)d_in[3];
  const float* Wo = (const float*)d_in[4];
  const float* Fq = (const float*)d_in[5];
  const float* Fk = (const float*)d_in[6];
  float* out = (float*)d_out;

  const size_t MD = (size_t)Mrows * Dc;  // 16,777,216
  const size_t DD = (size_t)Dc * Dc;     // 4,194,304 (MD == 4*DD)

  char* w = (char*)d_ws;
  size_t off = 0;
  auto take = [&](size_t bytes) -> void* {
    void* r = w + off;
    off += (bytes + 255) & ~(size_t)255;
    return r;
  };

  unsigned short* hs_bf = (unsigned short*)take(MD * 2);  // reused as attnbf
  // 4 contiguous DD buffers == MD elems; dead after gemm_pair -> reused as Qp
  unsigned short* wq_bf = (unsigned short*)take(DD * 2);
  unsigned short* wtfq  = (unsigned short*)take(DD * 2);
  unsigned short* wk_bf = (unsigned short*)take(DD * 2);
  unsigned short* wtfk  = (unsigned short*)take(DD * 2);
  unsigned short* wcat  = (unsigned short*)take(3 * DD * 2);  // [Wqf^T|Wkf^T|Wv^T]
  unsigned short* wto   = (unsigned short*)take(DD * 2);
  unsigned short* Kp    = (unsigned short*)take(MD * 2);
  unsigned short* Vbf   = (unsigned short*)take(MD * 2);
  float* dotb = (float*)take((size_t)Bc * Hc * Tc * 4);
  float* chks = (float*)take((size_t)Bc * Hc * NCHUNK * HDc * 4);

  // aliases (stream-ordered reuse)
  unsigned short* Qp = wq_bf;        // over the 4 dead weight buffers (4*DD == MD)
  unsigned short* attnbf = hs_bf;    // hs_bf dead after fused QKV GEMM

  const float OFF = (float)(-0.5 * log(2048.0) + 1e-6);

  // allow 128 KiB dynamic LDS (defensive; ignore errors)
  (void)hipFuncSetAttribute((const void*)gemm256<0>, hipFuncAttributeMaxDynamicSharedMemorySize, 131072);
  (void)hipFuncSetAttribute((const void*)gemm256<3>, hipFuncAttributeMaxDynamicSharedMemorySize, 131072);

  // 1) convert activations + plain-layout Wq, Wk
  cvt_bf16<<<(int)(MD / 1024), 256, 0, stream>>>(hs, hs_bf);
  cvt_bf16<<<(int)(DD / 1024), 256, 0, stream>>>(Wq, wq_bf);
  cvt_bf16<<<(int)(DD / 1024), 256, 0, stream>>>(Wk, wk_bf);

  // 2) transpose+convert Fq, Fk, Wv, Wo
  dim3 tg(Dc / 32, Dc / 32);
  transpose_cvt<<<tg, 256, 0, stream>>>(Fq, wtfq);
  transpose_cvt<<<tg, 256, 0, stream>>>(Fk, wtfk);
  transpose_cvt<<<tg, 256, 0, stream>>>(Wv, wcat + 2 * DD);
  transpose_cvt<<<tg, 256, 0, stream>>>(Wo, wto);

  // 3) weight products: wcat[0:DD) = Fq^T*Wq^T = (Wq*Fq)^T; wcat[DD:2DD) same for K
  gemm_pair<<<dim3(256, 2), 256, 0, stream>>>(wtfq, wq_bf, wcat,
                                              wtfk, wk_bf, wcat + DD);

  // 4) fused QKV GEMM: hs @ [Wqf|Wkf|Wv], epilogue exp/exp/plain -> Qp,Kp,Vbf
  const int fblocks = (Mrows / 256) * (6144 / 256);  // 768
  gemm256<3><<<fblocks, 512, 131072, stream>>>(hs_bf, wcat, Qp, Kp, Vbf,
                                               Mrows, 6144, Dc, Dc, OFF);

  // 5) per-position dot over each head
  dot_kernel<<<1024, 256, 0, stream>>>(Qp, Kp, dotb);

  // 6) chunked causal cumsum + divide, write bf16 attn (merged layout)
  scan_chunks<<<Bc * Hc * NCHUNK, 128, 0, stream>>>(dotb, Vbf, chks);
  scan_offsets<<<Bc * Hc, 128, 0, stream>>>(chks);
  scan_final<<<Bc * Hc * NCHUNK, 128, 0, stream>>>(dotb, Vbf, Kp, chks, attnbf);

  // 7) output projection (fp32 out)
  const int gblocks = (Mrows / 256) * (Dc / 256);  // 256
  gemm256<0><<<gblocks, 512, 131072, stream>>>(attnbf, wto, out, nullptr, nullptr,
                                               Mrows, Dc, Dc, Dc, 0.f);
}

// Round 5
// 443.885 us; speedup vs baseline: 1.7923x; 1.0011x over previous
//
#include <hip/hip_runtime.h>
#include <hip/hip_bf16.h>
#include <cmath>

// Problem constants
constexpr int Bc = 2, Tc = 4096, Dc = 2048, Hc = 16, HDc = 128;
constexpr int Mrows = Bc * Tc;            // 8192
constexpr int NCHUNK = 32, CHUNK = 128;   // T = NCHUNK * CHUNK

// ---------- small helpers ----------
__device__ __forceinline__ unsigned short f2bf(float x) {
  union { float f; unsigned int u; } v; v.f = x;
  unsigned int r = v.u + 0x7FFFu + ((v.u >> 16) & 1u);  // RNE
  return (unsigned short)(r >> 16);
}
__device__ __forceinline__ float bf2f(unsigned short u) {
  union { unsigned int i; float f; } v; v.i = ((unsigned int)u) << 16;
  return v.f;
}

typedef __attribute__((ext_vector_type(8))) short bf16x8;
typedef __attribute__((ext_vector_type(4))) float f32x4;

__device__ __forceinline__ void gload16(const unsigned short* g, unsigned short* l) {
  __builtin_amdgcn_global_load_lds(
      (const __attribute__((address_space(1))) void*)(const void*)g,
      (__attribute__((address_space(3))) void*)(void*)l,
      16, 0, 0);
}

// ---------- fp32 -> bf16 convert (vectorized) ----------
__global__ void cvt_bf16(const float* __restrict__ in, unsigned short* __restrict__ outp) {
  size_t i = ((size_t)blockIdx.x * 256 + threadIdx.x) * 4;
  float4 f = *(const float4*)(in + i);
  ushort4 u;
  u.x = f2bf(f.x); u.y = f2bf(f.y); u.z = f2bf(f.z); u.w = f2bf(f.w);
  *(ushort4*)(outp + i) = u;
}

// ---------- W [K][N] fp32 -> Wt [N][K] bf16 ----------
__global__ void transpose_cvt(const float* __restrict__ W, unsigned short* __restrict__ Wt) {
  __shared__ float tile[32][33];
  int n0 = blockIdx.x * 32, k0 = blockIdx.y * 32;
  int tx = threadIdx.x & 31, ty = threadIdx.x >> 5;  // ty: 0..7
#pragma unroll
  for (int i = 0; i < 4; ++i)
    tile[ty + 8 * i][tx] = W[(size_t)(k0 + ty + 8 * i) * Dc + n0 + tx];
  __syncthreads();
#pragma unroll
  for (int i = 0; i < 4; ++i)
    Wt[(size_t)(n0 + ty + 8 * i) * Dc + k0 + tx] = f2bf(tile[tx][ty + 8 * i]);
}

// ============================================================================
// Deep-pipelined GEMM template: C[M,N] = A[M,K](bf16, lda) * Bt[N,K](bf16)^T
// K hardcoded 2048, BK=32 K-tiles, QUAD-buffered LDS, stage tile v+3 during
// tile v (3 tiles / 12 loads in flight), counted vmcnt(8) once per K-tile.
// XOR bank-conflict swizzle: source-side for staging (LDS dest stays linear,
// required by global_load_lds) + folded into per-lane fragment read offsets.
// Wave grid WMw x WNw, per-wave tile (MI*16) x (NI*16).
// EPI: 0 = fp32 store, 1 = bf16 store,
//      3 = fused QKV (N=6144, BN=256): seg0->exp->C0, seg1->exp->C1, seg2->C2
// z-batch: blockIdx.y==1 switches to (A1,B1,C1a) (used for the weight pair).
// ============================================================================
template <int EPI, int WMw, int WNw, int MI, int NI>
__global__ __launch_bounds__(WMw * WNw * 64, 2) void gemmP(
    const unsigned short* __restrict__ A0, const unsigned short* __restrict__ B0,
    void* __restrict__ C0, void* __restrict__ C1, void* __restrict__ C2,
    const unsigned short* __restrict__ A1, const unsigned short* __restrict__ B1,
    void* __restrict__ C1a,
    int M, int N, int lda, int ldc, float eoff) {
  constexpr int K = 2048;
  constexpr int NT = K / 32;                 // 64 K-tiles
  constexpr int THREADS = WMw * WNw * 64;
  constexpr int BM = WMw * MI * 16;
  constexpr int BN = WNw * NI * 16;
  constexpr int ASLAB = BM * 32;             // elems per A K-slab
  constexpr int BSLAB = BN * 32;
  constexpr int BUF = ASLAB + BSLAB;         // one K-tile buffer
  constexpr int SROWS = THREADS / 4;         // rows staged per gload pass
  static_assert(2 * SROWS == BM && BM == BN, "staging geometry");
  extern __shared__ unsigned short lds[];    // 4 * BUF elems

  const unsigned short* A = A0;
  const unsigned short* Bt = B0;
  void* Cz = C0;
  if (blockIdx.y) { A = A1; Bt = B1; Cz = C1a; }

  const int tid = threadIdx.x;
  const int lane = tid & 63;
  const int wave = tid >> 6;
  const int wm = wave / WNw;
  const int wn = wave % WNw;

  const int nbn = N / BN;
  const int nwg = (M / BM) * nbn;
  const int bidx = (int)blockIdx.x;
  const int wgid = (bidx & 7) * (nwg >> 3) + (bidx >> 3);  // XCD swizzle (nwg%8==0)
  const int bm = wgid / nbn;
  const int bn = wgid % nbn;

  // ---- staging addressing: one K-slab = BM rows x 32 bf16 (64B rows)
  const int srow = tid >> 2;                    // 0..SROWS-1
  const int scolL = (tid & 3) << 3;             // linear LDS col (elems)
  const int scolG = scolL ^ ((srow & 6) << 2);  // pre-swizzled global source col
  const unsigned short* gA = A + (size_t)(bm * BM + srow) * lda + scolG;
  const unsigned short* gB = Bt + (size_t)(bn * BN + srow) * K + scolG;
  const int sstage = srow * 32 + scolL;         // LDS elem offset (linear dest)
  const size_t arstep = (size_t)SROWS * lda;    // +SROWS rows (2nd gload pass)
  const size_t brstep = (size_t)SROWS * K;

  // ---- fragment read offsets (within a K-tile buffer), swizzle folded
  const int fr = lane & 15;
  const int fko = ((lane >> 4) << 3) ^ ((lane & 6) << 2);
  const int aoff = (wm * MI * 16 + fr) * 32 + fko;           // + mi*512
  const int boff = ASLAB + (wn * NI * 16 + fr) * 32 + fko;   // + ni*512

  f32x4 acc[MI][NI] = {};
  bf16x8 afr[MI / 2];
  bf16x8 bfr[NI];

  // ---- prologue: stage tiles 0,1,2 (12 loads)
#pragma unroll
  for (int t = 0; t < 3; ++t) {
    const unsigned short* sA = gA + t * 32;
    const unsigned short* sB = gB + t * 32;
    unsigned short* dst = lds + t * BUF;
    gload16(sA,          dst + sstage);
    gload16(sA + arstep, dst + sstage + SROWS * 32);
    gload16(sB,          dst + ASLAB + sstage);
    gload16(sB + brstep, dst + ASLAB + sstage + SROWS * 32);
  }
  asm volatile("s_waitcnt vmcnt(8)" ::: "memory");  // tile 0 landed
  __builtin_amdgcn_s_barrier();

  for (int v = 0; v < NT; ++v) {
    const int rb = (v & 3) * BUF;            // read buffer
    const int wb = ((v + 3) & 3) * BUF;      // stage buffer (tile v+3)
    const int tn = (v + 3) & (NT - 1);       // wrap-stage near tail: harmless
    const unsigned short* srcA = gA + tn * 32;
    const unsigned short* srcB = gB + tn * 32;

    // ===== phase 1: mi 0..MI/2-1 x ni 0..NI-1 =====
    {
#pragma unroll
      for (int mi = 0; mi < MI / 2; ++mi)
        afr[mi] = *(const bf16x8*)(lds + rb + aoff + mi * 512);
#pragma unroll
      for (int ni = 0; ni < NI; ++ni)
        bfr[ni] = *(const bf16x8*)(lds + rb + boff + ni * 512);
      gload16(srcA,          lds + wb + sstage);            // stage A(tile v+3)
      gload16(srcA + arstep, lds + wb + sstage + SROWS * 32);
      __builtin_amdgcn_s_barrier();
      asm volatile("s_waitcnt lgkmcnt(0)" ::: "memory");
      __builtin_amdgcn_s_setprio(1);
#pragma unroll
      for (int mi = 0; mi < MI / 2; ++mi)
#pragma unroll
        for (int ni = 0; ni < NI; ++ni)
          acc[mi][ni] = __builtin_amdgcn_mfma_f32_16x16x32_bf16(afr[mi], bfr[ni], acc[mi][ni], 0, 0, 0);
      __builtin_amdgcn_s_setprio(0);
      __builtin_amdgcn_s_barrier();
    }
    // ===== phase 2: mi MI/2..MI-1 x ni 0..NI-1 (bfr reused) =====
    {
#pragma unroll
      for (int mi = 0; mi < MI / 2; ++mi)
        afr[mi] = *(const bf16x8*)(lds + rb + aoff + (MI / 2 + mi) * 512);
      gload16(srcB,          lds + wb + ASLAB + sstage);    // stage B(tile v+3)
      gload16(srcB + brstep, lds + wb + ASLAB + sstage + SROWS * 32);
      asm volatile("s_waitcnt vmcnt(8)" ::: "memory");      // tile v+1 landed
      __builtin_amdgcn_s_barrier();
      asm volatile("s_waitcnt lgkmcnt(0)" ::: "memory");
      __builtin_amdgcn_s_setprio(1);
#pragma unroll
      for (int mi = 0; mi < MI / 2; ++mi)
#pragma unroll
        for (int ni = 0; ni < NI; ++ni)
          acc[MI / 2 + mi][ni] = __builtin_amdgcn_mfma_f32_16x16x32_bf16(afr[mi], bfr[ni], acc[MI / 2 + mi][ni], 0, 0, 0);
      __builtin_amdgcn_s_setprio(0);
      __builtin_amdgcn_s_barrier();
    }
  }

  // ---- epilogue
  const int fq = lane >> 4;
  const int crow = bm * BM + wm * (MI * 16);
  if constexpr (EPI == 3) {
    const int seg = bn >> 3;  // 0:Q 1:K 2:V   (BN=256, 8 col-blocks/segment)
    unsigned short* outp = (unsigned short*)(seg == 0 ? C0 : (seg == 1 ? C1 : C2));
    const int ccol = (bn & 7) * BN + wn * (NI * 16) + fr;
#pragma unroll
    for (int mi = 0; mi < MI; ++mi)
#pragma unroll
      for (int ni = 0; ni < NI; ++ni)
#pragma unroll
        for (int ii = 0; ii < 4; ++ii) {
          const int r = crow + mi * 16 + fq * 4 + ii;
          const int c = ccol + ni * 16;
          float vv = acc[mi][ni][ii];
          if (seg < 2) vv = __expf(vv + eoff);
          outp[(size_t)r * ldc + c] = f2bf(vv);
        }
  } else {
    const int ccol = bn * BN + wn * (NI * 16) + fr;
#pragma unroll
    for (int mi = 0; mi < MI; ++mi)
#pragma unroll
      for (int ni = 0; ni < NI; ++ni)
#pragma unroll
        for (int ii = 0; ii < 4; ++ii) {
          const int r = crow + mi * 16 + fq * 4 + ii;
          const int c = ccol + ni * 16;
          const size_t idx = (size_t)r * ldc + c;
          float vv = acc[mi][ni][ii];
          if (EPI == 0) ((float*)Cz)[idx] = vv;
          else          ((unsigned short*)Cz)[idx] = f2bf(vv);
        }
  }
}

// ---------- dot[b,h,t] = sum_d qp[.]*kp[.] ----------
__global__ void dot_kernel(const unsigned short* __restrict__ qp,
                           const unsigned short* __restrict__ kp,
                           float* __restrict__ dotb) {
  const int BHT = Bc * Hc * Tc;  // 131072
  const int lane = threadIdx.x & 63;
  const int qw = lane >> 4;      // quarter-wave index 0..3
  const int j = lane & 15;       // 8-elem group within row
  const int gw = (blockIdx.x * blockDim.x + threadIdx.x) >> 6;  // global wave
  const int nw = (gridDim.x * blockDim.x) >> 6;

  for (int flat = gw * 4 + qw; flat < BHT; flat += nw * 4) {
    const int bh = flat >> 12;        // /T
    const int t = flat & (Tc - 1);
    const int b = bh >> 4, h = bh & 15;
    const size_t base = ((size_t)(b * Tc + t)) * Dc + h * HDc + j * 8;
    bf16x8 q = *(const bf16x8*)(qp + base);
    bf16x8 k = *(const bf16x8*)(kp + base);
    float p = 0.f;
#pragma unroll
    for (int i = 0; i < 8; ++i)
      p += bf2f((unsigned short)q[i]) * bf2f((unsigned short)k[i]);
#pragma unroll
    for (int m = 8; m; m >>= 1) p += __shfl_xor(p, m);
    if (j == 0) dotb[flat] = p;
  }
}

// ---------- chunked scan: pass 1 (per-chunk sums) ----------
__global__ void scan_chunks(const float* __restrict__ dotb,
                            const unsigned short* __restrict__ v,
                            float* __restrict__ chks) {
  int bid = blockIdx.x;            // bh*NCHUNK + c
  int c = bid % NCHUNK, bh = bid / NCHUNK;
  int b = bh / Hc, h = bh % Hc;
  int d = threadIdx.x;
  const float* dp = dotb + (size_t)bh * Tc + c * CHUNK;
  const unsigned short* vp = v + ((size_t)(b * Tc + c * CHUNK)) * Dc + h * HDc + d;
  float acc = 0.f;
  for (int t = 0; t < CHUNK; ++t)
    acc += dp[t] * bf2f(vp[(size_t)t * Dc]);
  chks[(size_t)bid * HDc + d] = acc;
}

// ---------- chunked scan: pass 2 (exclusive scan of chunk sums) ----------
__global__ void scan_offsets(float* __restrict__ chks) {
  int bh = blockIdx.x;
  int d = threadIdx.x;
  float run = 0.f;
  for (int c = 0; c < NCHUNK; ++c) {
    size_t idx = ((size_t)bh * NCHUNK + c) * HDc + d;
    float tmp = chks[idx];
    chks[idx] = run;
    run += tmp;
  }
}

// ---------- chunked scan: pass 3 (final prefix + divide by kp, bf16 out) ----------
__global__ void scan_final(const float* __restrict__ dotb,
                           const unsigned short* __restrict__ v,
                           const unsigned short* __restrict__ kp,
                           const float* __restrict__ chks,
                           unsigned short* __restrict__ attn) {
  int bid = blockIdx.x;
  int c = bid % NCHUNK, bh = bid / NCHUNK;
  int b = bh / Hc, h = bh % Hc;
  int d = threadIdx.x;
  const float* dp = dotb + (size_t)bh * Tc + c * CHUNK;
  size_t base = ((size_t)(b * Tc + c * CHUNK)) * Dc + h * HDc + d;
  float acc = chks[(size_t)bid * HDc + d];
  for (int t = 0; t < CHUNK; ++t) {
    size_t idx = base + (size_t)t * Dc;
    acc += dp[t] * bf2f(v[idx]);
    attn[idx] = f2bf(acc / bf2f(kp[idx]));
  }
}

// ---------- launch ----------
extern "C" void kernel_launch(void* const* d_in, const int* in_sizes, int n_in,
                              void* d_out, int out_size, void* d_ws, size_t ws_size,
                              hipStream_t stream) {
  const float* hs = (const float*)d_in[0];
  const float* Wq = (const float*)d_in[1];
  const float* Wk = (const float*)d_in[2];
  const float* Wv = (const float*)d_in[3];
  const float* Wo = (const float*)d_in[4];
  const float* Fq = (const float*)d_in[5];
  const float* Fk = (const float*)d_in[6];
  float* out = (float*)d_out;

  const size_t MD = (size_t)Mrows * Dc;  // 16,777,216
  const size_t DD = (size_t)Dc * Dc;     // 4,194,304 (MD == 4*DD)

  char* w = (char*)d_ws;
  size_t off = 0;
  auto take = [&](size_t bytes) -> void* {
    void* r = w + off;
    off += (bytes + 255) & ~(size_t)255;
    return r;
  };

  unsigned short* hs_bf = (unsigned short*)take(MD * 2);  // reused as attnbf
  // 4 contiguous DD buffers == MD elems; dead after weight-pair -> reused as Qp
  unsigned short* wq_bf = (unsigned short*)take(DD * 2);
  unsigned short* wtfq  = (unsigned short*)take(DD * 2);
  unsigned short* wk_bf = (unsigned short*)take(DD * 2);
  unsigned short* wtfk  = (unsigned short*)take(DD * 2);
  unsigned short* wcat  = (unsigned short*)take(3 * DD * 2);  // [Wqf^T|Wkf^T|Wv^T]
  unsigned short* wto   = (unsigned short*)take(DD * 2);
  unsigned short* Kp    = (unsigned short*)take(MD * 2);
  unsigned short* Vbf   = (unsigned short*)take(MD * 2);
  float* dotb = (float*)take((size_t)Bc * Hc * Tc * 4);
  float* chks = (float*)take((size_t)Bc * Hc * NCHUNK * HDc * 4);

  // aliases (stream-ordered reuse)
  unsigned short* Qp = wq_bf;        // over the 4 dead weight buffers (4*DD == MD)
  unsigned short* attnbf = hs_bf;    // hs_bf dead after fused QKV GEMM

  const float OFF = (float)(-0.5 * log(2048.0) + 1e-6);

  // allow dynamic LDS (defensive; ignore errors)
  (void)hipFuncSetAttribute((const void*)gemmP<0, 2, 4, 8, 4>, hipFuncAttributeMaxDynamicSharedMemorySize, 131072);
  (void)hipFuncSetAttribute((const void*)gemmP<3, 2, 4, 8, 4>, hipFuncAttributeMaxDynamicSharedMemorySize, 131072);
  (void)hipFuncSetAttribute((const void*)gemmP<1, 2, 2, 4, 4>, hipFuncAttributeMaxDynamicSharedMemorySize, 65536);

  // 1) convert activations + plain-layout Wq, Wk
  cvt_bf16<<<(int)(MD / 1024), 256, 0, stream>>>(hs, hs_bf);
  cvt_bf16<<<(int)(DD / 1024), 256, 0, stream>>>(Wq, wq_bf);
  cvt_bf16<<<(int)(DD / 1024), 256, 0, stream>>>(Wk, wk_bf);

  // 2) transpose+convert Fq, Fk, Wv, Wo
  dim3 tg(Dc / 32, Dc / 32);
  transpose_cvt<<<tg, 256, 0, stream>>>(Fq, wtfq);
  transpose_cvt<<<tg, 256, 0, stream>>>(Fk, wtfk);
  transpose_cvt<<<tg, 256, 0, stream>>>(Wv, wcat + 2 * DD);
  transpose_cvt<<<tg, 256, 0, stream>>>(Wo, wto);

  // 3) weight products (z-batched, 128^2 tiles, 2 blocks/CU):
  //    wcat[0:DD) = Fq^T @ Wq^T = (Wq@Fq)^T ; wcat[DD:2DD) same for K
  gemmP<1, 2, 2, 4, 4><<<dim3(256, 2), 256, 65536, stream>>>(
      wtfq, wq_bf, wcat, nullptr, nullptr,
      wtfk, wk_bf, wcat + DD,
      2048, 2048, 2048, 2048, 0.f);

  // 4) fused QKV GEMM: hs @ [Wqf|Wkf|Wv], epilogue exp/exp/plain -> Qp,Kp,Vbf
  const int fblocks = (Mrows / 256) * (6144 / 256);  // 768
  gemmP<3, 2, 4, 8, 4><<<fblocks, 512, 131072, stream>>>(
      hs_bf, wcat, Qp, Kp, Vbf, nullptr, nullptr, nullptr,
      Mrows, 6144, Dc, Dc, OFF);

  // 5) per-position dot over each head
  dot_kernel<<<1024, 256, 0, stream>>>(Qp, Kp, dotb);

  // 6) chunked causal cumsum + divide, write bf16 attn (merged layout)
  scan_chunks<<<Bc * Hc * NCHUNK, 128, 0, stream>>>(dotb, Vbf, chks);
  scan_offsets<<<Bc * Hc, 128, 0, stream>>>(chks);
  scan_final<<<Bc * Hc * NCHUNK, 128, 0, stream>>>(dotb, Vbf, Kp, chks, attnbf);

  // 7) output projection (fp32 out)
  const int gblocks = (Mrows / 256) * (Dc / 256);  // 256
  gemmP<0, 2, 4, 8, 4><<<gblocks, 512, 131072, stream>>>(
      attnbf, wto, out, nullptr, nullptr, nullptr, nullptr, nullptr,
      Mrows, Dc, Dc, Dc, 0.f);
}